// Round 3
// baseline (3455.493 us; speedup 1.0000x reference)
//
#include <hip/hip_runtime.h>
#include <math.h>

#define D64 64
#define ES16 16
#define NB5 256

__device__ __forceinline__ float sigf(float x){ return 1.0f/(1.0f + __expf(-x)); }
__device__ __forceinline__ float tanhfast(float x){ return 2.0f*sigf(2.0f*x) - 1.0f; }

// ---------------- CSR build ----------------
__global__ void k_count(const int* __restrict__ u, const int* __restrict__ v,
                        int* __restrict__ cnt, int N, int E){
  int e = blockIdx.x*256 + threadIdx.x;
  if(e < E){
    atomicAdd(&cnt[v[e]], 1);
    atomicAdd(&cnt[N + u[e]], 1);
  }
}

__global__ void k_scan1(const int* __restrict__ cnt, int* __restrict__ part, int M){
  __shared__ int sm[256];
  int i = blockIdx.x*256 + threadIdx.x;
  sm[threadIdx.x] = (i < M) ? cnt[i] : 0;
  __syncthreads();
  for(int s = 128; s > 0; s >>= 1){
    if(threadIdx.x < s) sm[threadIdx.x] += sm[threadIdx.x + s];
    __syncthreads();
  }
  if(threadIdx.x == 0) part[blockIdx.x] = sm[0];
}

__global__ void k_scan2(int* __restrict__ part, int nb){
  __shared__ int sm[1024];
  int t = threadIdx.x;
  int orig = (t < nb) ? part[t] : 0;
  sm[t] = orig;
  __syncthreads();
  for(int off = 1; off < 1024; off <<= 1){
    int add = (t >= off) ? sm[t - off] : 0;
    __syncthreads();
    sm[t] += add;
    __syncthreads();
  }
  if(t < nb) part[t] = sm[t] - orig;  // exclusive prefix
}

__global__ void k_scan3(int* __restrict__ cnt, const int* __restrict__ part,
                        int* __restrict__ cur, int M, int total){
  __shared__ int sm[256];
  int t = threadIdx.x;
  int i = blockIdx.x*256 + t;
  int orig = (i < M) ? cnt[i] : 0;
  sm[t] = orig;
  __syncthreads();
  for(int off = 1; off < 256; off <<= 1){
    int add = (t >= off) ? sm[t - off] : 0;
    __syncthreads();
    sm[t] += add;
    __syncthreads();
  }
  if(i < M){
    int excl = part[blockIdx.x] + sm[t] - orig;
    cnt[i] = excl;
    cur[i] = excl;
  }
  if(i == 0) cnt[M] = total;
}

__global__ void k_fill(const int* __restrict__ u, const int* __restrict__ v,
                       int* __restrict__ cur, int* __restrict__ rows, int N, int E){
  int e = blockIdx.x*256 + threadIdx.x;
  if(e < E){
    int p = atomicAdd(&cur[v[e]], 1); rows[p] = e;
    int q = atomicAdd(&cur[N + u[e]], 1); rows[q] = e;
  }
}

// ---------------- round-constant edge-feature sums ----------------
__global__ void k_einout(const float* __restrict__ ev, const int* __restrict__ off,
                         const int* __restrict__ rows,
                         float* __restrict__ Ein, float* __restrict__ Eout, int N){
  int n = (blockIdx.x*blockDim.x + threadIdx.x) >> 6;
  int lane = threadIdx.x & 63;
  if(n >= N) return;
  int t = lane & 15, s = lane >> 4;
  float a = 0.f;
  int p1 = off[n+1];
  for(int p = off[n] + s; p < p1; p += 4) a += ev[rows[p]*ES16 + t];
  a += __shfl_xor(a, 16, 64);
  a += __shfl_xor(a, 32, 64);
  if(lane < 16) Ein[n*ES16 + lane] = a;
  float b = 0.f;
  p1 = off[N+n+1];
  for(int p = off[N+n] + s; p < p1; p += 4) b += ev[rows[p]*ES16 + t];
  b += __shfl_xor(b, 16, 64);
  b += __shfl_xor(b, 32, 64);
  if(lane < 16) Eout[n*ES16 + lane] = b;
}

// ---------------- per-round sparse aggregation (wave per node) ----------------
__global__ void k_aggr(const float* __restrict__ h, const int* __restrict__ off,
                       const int* __restrict__ rows, const int* __restrict__ uidx,
                       const int* __restrict__ vidx,
                       float* __restrict__ Sin, float* __restrict__ Sout, int N){
  int n = (blockIdx.x*blockDim.x + threadIdx.x) >> 6;
  int lane = threadIdx.x & 63;
  if(n >= N) return;
  {
    float s = 0.f;
    int p = off[n], p1 = off[n+1];
    for(; p + 2 <= p1; p += 2){
      int e0 = rows[p], e1 = rows[p+1];
      float a = h[uidx[e0]*D64 + lane];
      float b = h[uidx[e1]*D64 + lane];
      s += a + b;
    }
    if(p < p1) s += h[uidx[rows[p]]*D64 + lane];
    Sin[n*D64 + lane] = s;
  }
  {
    float s = 0.f;
    int p = off[N+n], p1 = off[N+n+1];
    for(; p + 2 <= p1; p += 2){
      int e0 = rows[p], e1 = rows[p+1];
      float a = h[vidx[e0]*D64 + lane];
      float b = h[vidx[e1]*D64 + lane];
      s += a + b;
    }
    if(p < p1) s += h[vidx[rows[p]]*D64 + lane];
    Sout[n*D64 + lane] = s;
  }
}

// ---------------- node transform: agg = Wef*xf + Wer*xr + deg*biases ----------------
// 512 threads = 8 waves; wave wv computes jt = {wv, wv+8}.
// LDS rows: 0..63 Sin | 64..127 h | 128..191 Sout. Ein/Eout/deg read from global.
__global__ __launch_bounds__(512, 6) void k3_agg(
    const float* __restrict__ h, const float* __restrict__ Sin,
    const float* __restrict__ Sout, const float* __restrict__ Ein,
    const float* __restrict__ Eout, const int* __restrict__ off,
    const float* __restrict__ Wef, const float* __restrict__ bef,
    const float* __restrict__ Wer, const float* __restrict__ ber,
    float* __restrict__ aggT, int N){
  __shared__ float xT[192][67];
  const int lane = threadIdx.x & 63;
  const int wv   = threadIdx.x >> 6;
  const int base = blockIdx.x * 64;
  for(int ii = 0; ii < 8; ++ii){
    int i = wv*8 + ii;
    int n = base + i; if(n >= N) n = N - 1;
    xT[lane][i]       = Sin[n*D64 + lane];
    xT[64+lane][i]    = h[n*D64 + lane];
    xT[128+lane][i]   = Sout[n*D64 + lane];
  }
  __syncthreads();
  int node = base + lane; if(node >= N) node = N - 1;
  const float fi = (float)(off[node+1] - off[node]);
  const float fo = (float)(off[N+node+1] - off[N+node]);
  const bool valid = (base + lane) < N;
  for(int t = 0; t < 2; ++t){
    const int jt = wv + t*8;
    float acc[8];
    #pragma unroll
    for(int jj = 0; jj < 8; ++jj){
      int j = jt*8 + jj;
      acc[jj] = fi*bef[j] + fo*ber[j];
    }
    // Sin block: Wef cols 0..63
    #pragma unroll 4
    for(int k4 = 0; k4 < 16; ++k4){
      float x0 = xT[k4*4+0][lane];
      float x1 = xT[k4*4+1][lane];
      float x2 = xT[k4*4+2][lane];
      float x3 = xT[k4*4+3][lane];
      #pragma unroll
      for(int jj = 0; jj < 8; ++jj){
        float4 w = *(const float4*)(Wef + (jt*8+jj)*144 + k4*4);
        acc[jj] = fmaf(w.x,x0,fmaf(w.y,x1,fmaf(w.z,x2,fmaf(w.w,x3,acc[jj]))));
      }
    }
    // h block: Wef cols 64..127 (×fi) and Wer cols 0..63 (×fo) share LDS reads
    #pragma unroll 2
    for(int k4 = 0; k4 < 16; ++k4){
      float h0 = xT[64+k4*4+0][lane];
      float h1 = xT[64+k4*4+1][lane];
      float h2 = xT[64+k4*4+2][lane];
      float h3 = xT[64+k4*4+3][lane];
      float f0 = fi*h0, f1 = fi*h1, f2 = fi*h2, f3 = fi*h3;
      float r0 = fo*h0, r1 = fo*h1, r2 = fo*h2, r3 = fo*h3;
      #pragma unroll
      for(int jj = 0; jj < 8; ++jj){
        int j = jt*8 + jj;
        float4 wf = *(const float4*)(Wef + j*144 + 64 + k4*4);
        float4 wr = *(const float4*)(Wer + j*144 + k4*4);
        acc[jj] = fmaf(wf.x,f0,fmaf(wf.y,f1,fmaf(wf.z,f2,fmaf(wf.w,f3,acc[jj]))));
        acc[jj] = fmaf(wr.x,r0,fmaf(wr.y,r1,fmaf(wr.z,r2,fmaf(wr.w,r3,acc[jj]))));
      }
    }
    // E blocks from global (L2-resident, per-lane rows)
    #pragma unroll
    for(int k4 = 0; k4 < 4; ++k4){
      float4 xi = *(const float4*)(Ein  + node*ES16 + k4*4);
      float4 xo = *(const float4*)(Eout + node*ES16 + k4*4);
      #pragma unroll
      for(int jj = 0; jj < 8; ++jj){
        int j = jt*8 + jj;
        float4 wf = *(const float4*)(Wef + j*144 + 128 + k4*4);
        float4 wr = *(const float4*)(Wer + j*144 + 128 + k4*4);
        acc[jj] = fmaf(wf.x,xi.x,fmaf(wf.y,xi.y,fmaf(wf.z,xi.z,fmaf(wf.w,xi.w,acc[jj]))));
        acc[jj] = fmaf(wr.x,xo.x,fmaf(wr.y,xo.y,fmaf(wr.z,xo.z,fmaf(wr.w,xo.w,acc[jj]))));
      }
    }
    // Sout block: Wer cols 64..127
    #pragma unroll 4
    for(int k4 = 0; k4 < 16; ++k4){
      float x0 = xT[128+k4*4+0][lane];
      float x1 = xT[128+k4*4+1][lane];
      float x2 = xT[128+k4*4+2][lane];
      float x3 = xT[128+k4*4+3][lane];
      #pragma unroll
      for(int jj = 0; jj < 8; ++jj){
        float4 w = *(const float4*)(Wer + (jt*8+jj)*144 + 64 + k4*4);
        acc[jj] = fmaf(w.x,x0,fmaf(w.y,x1,fmaf(w.z,x2,fmaf(w.w,x3,acc[jj]))));
      }
    }
    if(valid){
      #pragma unroll
      for(int jj = 0; jj < 8; ++jj)
        aggT[(size_t)(jt*8+jj)*N + base + lane] = acc[jj];
    }
  }
}

// ---------------- GRU: h' from aggT + h ----------------
// 512 threads = 8 waves; wave wv computes qt = wv, split in 2 halves of 4 outputs.
// xT rows 0..127 agg, 128..191 h; rows 0..63 reused as ht buffer after compute.
__global__ __launch_bounds__(512, 6) void k4_gru(
    const float* __restrict__ hcur, const float* __restrict__ aggT,
    const float* __restrict__ Wih, const float* __restrict__ Whh,
    const float* __restrict__ bih, const float* __restrict__ bhh,
    float* __restrict__ hnext, int N){
  __shared__ float xT[192][67];
  const int lane = threadIdx.x & 63;
  const int wv   = threadIdx.x >> 6;
  const int base = blockIdx.x * 64;
  {
    int n = base + lane; if(n >= N) n = N - 1;
    for(int kk = 0; kk < 16; ++kk){
      int k = wv*16 + kk;
      xT[k][lane] = aggT[(size_t)k*N + n];
    }
  }
  for(int ii = 0; ii < 8; ++ii){
    int i = wv*8 + ii;
    int n = base + i; if(n >= N) n = N - 1;
    xT[128 + lane][i] = hcur[n*D64 + lane];
  }
  __syncthreads();
  const int qt = wv;
  float hout[8];
  #pragma unroll
  for(int half = 0; half < 2; ++half){
    float aR[4], aZ[4], aN[4], aH[4];
    #pragma unroll
    for(int i = 0; i < 4; ++i){
      int q = qt*8 + half*4 + i;
      aR[i] = bih[q]      + bhh[q];
      aZ[i] = bih[64+q]   + bhh[64+q];
      aN[i] = bih[128+q];
      aH[i] = bhh[128+q];
    }
    #pragma unroll 2
    for(int k4 = 0; k4 < 32; ++k4){
      float x0 = xT[k4*4+0][lane];
      float x1 = xT[k4*4+1][lane];
      float x2 = xT[k4*4+2][lane];
      float x3 = xT[k4*4+3][lane];
      #pragma unroll
      for(int i = 0; i < 4; ++i){
        int q = qt*8 + half*4 + i;
        float4 wr = *(const float4*)(Wih + q*128       + k4*4);
        float4 wz = *(const float4*)(Wih + (64+q)*128  + k4*4);
        float4 wn = *(const float4*)(Wih + (128+q)*128 + k4*4);
        aR[i] = fmaf(wr.x,x0,fmaf(wr.y,x1,fmaf(wr.z,x2,fmaf(wr.w,x3,aR[i]))));
        aZ[i] = fmaf(wz.x,x0,fmaf(wz.y,x1,fmaf(wz.z,x2,fmaf(wz.w,x3,aZ[i]))));
        aN[i] = fmaf(wn.x,x0,fmaf(wn.y,x1,fmaf(wn.z,x2,fmaf(wn.w,x3,aN[i]))));
      }
    }
    #pragma unroll 2
    for(int k4 = 0; k4 < 16; ++k4){
      float x0 = xT[128+k4*4+0][lane];
      float x1 = xT[128+k4*4+1][lane];
      float x2 = xT[128+k4*4+2][lane];
      float x3 = xT[128+k4*4+3][lane];
      #pragma unroll
      for(int i = 0; i < 4; ++i){
        int q = qt*8 + half*4 + i;
        float4 wr = *(const float4*)(Whh + q*64       + k4*4);
        float4 wz = *(const float4*)(Whh + (64+q)*64  + k4*4);
        float4 wh = *(const float4*)(Whh + (128+q)*64 + k4*4);
        aR[i] = fmaf(wr.x,x0,fmaf(wr.y,x1,fmaf(wr.z,x2,fmaf(wr.w,x3,aR[i]))));
        aZ[i] = fmaf(wz.x,x0,fmaf(wz.y,x1,fmaf(wz.z,x2,fmaf(wz.w,x3,aZ[i]))));
        aH[i] = fmaf(wh.x,x0,fmaf(wh.y,x1,fmaf(wh.z,x2,fmaf(wh.w,x3,aH[i]))));
      }
    }
    #pragma unroll
    for(int i = 0; i < 4; ++i){
      int q = qt*8 + half*4 + i;
      float r = sigf(aR[i]);
      float z = sigf(aZ[i]);
      float nn = tanhfast(aN[i] + r*aH[i]);
      float hq = xT[128+q][lane];
      hout[half*4 + i] = (1.f - z)*nn + z*hq;
    }
  }
  __syncthreads();   // all reads of rows 0..63 done -> safe to reuse as ht
  #pragma unroll
  for(int i = 0; i < 8; ++i){
    int q = qt*8 + i;
    xT[q][lane] = hout[i];
  }
  __syncthreads();
  for(int ii = 0; ii < 8; ++ii){
    int i = wv*8 + ii;
    int n = base + i;
    if(n < N) hnext[n*D64 + lane] = xT[lane][i];
  }
}

// ---------------- gated readout: register-accumulated partials, no atomics ----------------
__global__ __launch_bounds__(512) void k5_read(
    const float* __restrict__ h, const float* __restrict__ Wfm,
    const float* __restrict__ bfm, const float* __restrict__ Wgm,
    const float* __restrict__ bgm, float* __restrict__ partials, int N, int nT){
  __shared__ float xT[64][67];
  const int lane = threadIdx.x & 63;
  const int wv   = threadIdx.x >> 6;
  float acc[2][8];
  #pragma unroll
  for(int t = 0; t < 2; ++t)
    #pragma unroll
    for(int jj = 0; jj < 8; ++jj) acc[t][jj] = 0.f;

  for(int tile = blockIdx.x; tile < nT; tile += NB5){
    const int base = tile * 64;
    __syncthreads();
    for(int ii = 0; ii < 8; ++ii){
      int i = wv*8 + ii;
      int n = base + i; if(n >= N) n = N - 1;
      xT[lane][i] = h[n*D64 + lane];
    }
    __syncthreads();
    const bool valid = (base + lane) < N;
    for(int t = 0; t < 2; ++t){
      const int jt = wv + t*8;
      float aF[8], aG[8];
      #pragma unroll
      for(int jj = 0; jj < 8; ++jj){
        int j = jt*8 + jj;
        aF[jj] = bfm[j]; aG[jj] = bgm[j];
      }
      #pragma unroll 2
      for(int k4 = 0; k4 < 16; ++k4){
        float x0 = xT[k4*4+0][lane];
        float x1 = xT[k4*4+1][lane];
        float x2 = xT[k4*4+2][lane];
        float x3 = xT[k4*4+3][lane];
        #pragma unroll
        for(int jj = 0; jj < 8; ++jj){
          int j = jt*8 + jj;
          float4 wf = *(const float4*)(Wfm + j*64 + k4*4);
          float4 wg = *(const float4*)(Wgm + j*64 + k4*4);
          aF[jj] = fmaf(wf.x,x0,fmaf(wf.y,x1,fmaf(wf.z,x2,fmaf(wf.w,x3,aF[jj]))));
          aG[jj] = fmaf(wg.x,x0,fmaf(wg.y,x1,fmaf(wg.z,x2,fmaf(wg.w,x3,aG[jj]))));
        }
      }
      if(valid){
        #pragma unroll
        for(int jj = 0; jj < 8; ++jj)
          acc[t][jj] += aF[jj] * sigf(aG[jj]);
      }
    }
  }
  #pragma unroll
  for(int t = 0; t < 2; ++t)
    for(int jj = 0; jj < 8; ++jj){
      float val = acc[t][jj];
      #pragma unroll
      for(int o = 32; o > 0; o >>= 1) val += __shfl_xor(val, o, 64);
      if(lane == 0) partials[blockIdx.x*128 + (wv + t*8)*8 + jj] = val;
    }
}

__global__ void k6_dec(const float* __restrict__ partials, int nb,
                       const float* __restrict__ h,
                       const float* __restrict__ Wdec, const float* __restrict__ bdec,
                       const int* __restrict__ tgt, float* __restrict__ out){
  __shared__ float sm[256];
  int t = threadIdx.x;
  float v = 0.f;
  if(t < 128){
    float s0 = 0.f, s1 = 0.f, s2 = 0.f, s3 = 0.f;
    for(int b = 0; b + 4 <= nb; b += 4){
      s0 += partials[(b+0)*128 + t];
      s1 += partials[(b+1)*128 + t];
      s2 += partials[(b+2)*128 + t];
      s3 += partials[(b+3)*128 + t];
    }
    v = ((s0 + s1) + (s2 + s3)) * Wdec[t];
  } else if(t < 192){
    v = h[tgt[0]*D64 + (t - 128)] * Wdec[t];
  }
  sm[t] = v;
  __syncthreads();
  for(int s = 128; s > 0; s >>= 1){
    if(t < s) sm[t] += sm[t + s];
    __syncthreads();
  }
  if(t == 0) out[0] = sm[0] + bdec[0];
}

extern "C" void kernel_launch(void* const* d_in, const int* in_sizes, int n_in,
                              void* d_out, int out_size, void* d_ws, size_t ws_size,
                              hipStream_t stream){
  const float* nodev = (const float*)d_in[0];
  const float* ev    = (const float*)d_in[1];
  const float* Wef   = (const float*)d_in[2];
  const float* bef   = (const float*)d_in[3];
  const float* Wer   = (const float*)d_in[4];
  const float* ber   = (const float*)d_in[5];
  const float* Wih   = (const float*)d_in[6];
  const float* Whh   = (const float*)d_in[7];
  const float* bih   = (const float*)d_in[8];
  const float* bhh   = (const float*)d_in[9];
  const float* Wfm   = (const float*)d_in[10];
  const float* bfm   = (const float*)d_in[11];
  const float* Wgm   = (const float*)d_in[12];
  const float* bgm   = (const float*)d_in[13];
  const float* Wdec  = (const float*)d_in[14];
  const float* bdec  = (const float*)d_in[15];
  const int* uidx    = (const int*)d_in[16];
  const int* vidx    = (const int*)d_in[17];
  const int* tgt     = (const int*)d_in[18];

  const int N = in_sizes[0] / 64;
  const int E = in_sizes[16];
  const int R = in_sizes[2] / (128*144);

  char* w = (char*)d_ws;
  auto alloc = [&](size_t bytes) -> void* {
    void* p = (void*)w;
    w += (bytes + 255) & ~(size_t)255;
    return p;
  };
  int* off       = (int*)alloc(((size_t)2*N + 1) * 4);
  int* cur       = (int*)alloc((size_t)2*N * 4);
  int* rows      = (int*)alloc((size_t)2*E * 4);
  int* part      = (int*)alloc(4096 * 4);
  float* Ein     = (float*)alloc((size_t)N*16*4);
  float* Eout    = (float*)alloc((size_t)N*16*4);
  float* Sin     = (float*)alloc((size_t)N*64*4);
  float* Sout    = (float*)alloc((size_t)N*64*4);
  float* hA      = (float*)alloc((size_t)N*64*4);
  float* hB      = (float*)alloc((size_t)N*64*4);
  float* aggT    = (float*)alloc((size_t)128*N*4);
  float* partial = (float*)alloc((size_t)NB5*128*4);

  hipMemsetAsync(off, 0, ((size_t)2*N+1)*4, stream);

  int eb = (E + 255)/256;
  k_count<<<eb, 256, 0, stream>>>(uidx, vidx, off, N, E);
  int M = 2*N;
  int nb = (M + 255)/256;
  k_scan1<<<nb, 256, 0, stream>>>(off, part, M);
  k_scan2<<<1, 1024, 0, stream>>>(part, nb);
  k_scan3<<<nb, 256, 0, stream>>>(off, part, cur, M, 2*E);
  k_fill<<<eb, 256, 0, stream>>>(uidx, vidx, cur, rows, N, E);
  int wb = (N + 3)/4;
  k_einout<<<wb, 256, 0, stream>>>(ev, off, rows, Ein, Eout, N);

  int nT = (N + 63)/64;
  const float* hcur = nodev;
  float* bufs[2] = {hA, hB};
  for(int r = 0; r < R; ++r){
    k_aggr<<<wb, 256, 0, stream>>>(hcur, off, rows, uidx, vidx, Sin, Sout, N);
    k3_agg<<<nT, 512, 0, stream>>>(hcur, Sin, Sout, Ein, Eout, off,
                                   Wef + (size_t)r*128*144, bef + r*128,
                                   Wer + (size_t)r*128*144, ber + r*128,
                                   aggT, N);
    float* hn = bufs[r & 1];
    k4_gru<<<nT, 512, 0, stream>>>(hcur, aggT,
                                   Wih + (size_t)r*192*128, Whh + (size_t)r*192*64,
                                   bih + r*192, bhh + r*192, hn, N);
    hcur = hn;
  }
  k5_read<<<NB5, 512, 0, stream>>>(hcur, Wfm, bfm, Wgm, bgm, partial, N, nT);
  k6_dec<<<1, 256, 0, stream>>>(partial, NB5, hcur, Wdec, bdec, tgt, (float*)d_out);
}

// Round 4
// 2478.197 us; speedup vs baseline: 1.3944x; 1.3944x over previous
//
#include <hip/hip_runtime.h>
#include <math.h>

#define D64 64
#define ES16 16
#define NB5 256

__device__ __forceinline__ float sigf(float x){ return 1.0f/(1.0f + __expf(-x)); }
__device__ __forceinline__ float tanhfast(float x){ return 2.0f*sigf(2.0f*x) - 1.0f; }

// ---------------- CSR build ----------------
__global__ void k_count(const int* __restrict__ u, const int* __restrict__ v,
                        int* __restrict__ cnt, int N, int E){
  int e = blockIdx.x*256 + threadIdx.x;
  if(e < E){
    atomicAdd(&cnt[v[e]], 1);
    atomicAdd(&cnt[N + u[e]], 1);
  }
}

__global__ void k_scan1(const int* __restrict__ cnt, int* __restrict__ part, int M){
  __shared__ int sm[256];
  int i = blockIdx.x*256 + threadIdx.x;
  sm[threadIdx.x] = (i < M) ? cnt[i] : 0;
  __syncthreads();
  for(int s = 128; s > 0; s >>= 1){
    if(threadIdx.x < s) sm[threadIdx.x] += sm[threadIdx.x + s];
    __syncthreads();
  }
  if(threadIdx.x == 0) part[blockIdx.x] = sm[0];
}

__global__ void k_scan2(int* __restrict__ part, int nb){
  __shared__ int sm[1024];
  int t = threadIdx.x;
  int orig = (t < nb) ? part[t] : 0;
  sm[t] = orig;
  __syncthreads();
  for(int off = 1; off < 1024; off <<= 1){
    int add = (t >= off) ? sm[t - off] : 0;
    __syncthreads();
    sm[t] += add;
    __syncthreads();
  }
  if(t < nb) part[t] = sm[t] - orig;  // exclusive prefix
}

__global__ void k_scan3(int* __restrict__ cnt, const int* __restrict__ part,
                        int* __restrict__ cur, int M, int total){
  __shared__ int sm[256];
  int t = threadIdx.x;
  int i = blockIdx.x*256 + t;
  int orig = (i < M) ? cnt[i] : 0;
  sm[t] = orig;
  __syncthreads();
  for(int off = 1; off < 256; off <<= 1){
    int add = (t >= off) ? sm[t - off] : 0;
    __syncthreads();
    sm[t] += add;
    __syncthreads();
  }
  if(i < M){
    int excl = part[blockIdx.x] + sm[t] - orig;
    cnt[i] = excl;
    cur[i] = excl;
  }
  if(i == 0) cnt[M] = total;
}

__global__ void k_fill(const int* __restrict__ u, const int* __restrict__ v,
                       int* __restrict__ cur, int* __restrict__ rows, int N, int E){
  int e = blockIdx.x*256 + threadIdx.x;
  if(e < E){
    int p = atomicAdd(&cur[v[e]], 1); rows[p] = e;
    int q = atomicAdd(&cur[N + u[e]], 1); rows[q] = e;
  }
}

// ---------------- round-constant edge-feature sums ----------------
__global__ void k_einout(const float* __restrict__ ev, const int* __restrict__ off,
                         const int* __restrict__ rows,
                         float* __restrict__ Ein, float* __restrict__ Eout, int N){
  int n = (blockIdx.x*blockDim.x + threadIdx.x) >> 6;
  int lane = threadIdx.x & 63;
  if(n >= N) return;
  int t = lane & 15, s = lane >> 4;
  float a = 0.f;
  int p1 = off[n+1];
  for(int p = off[n] + s; p < p1; p += 4) a += ev[rows[p]*ES16 + t];
  a += __shfl_xor(a, 16, 64);
  a += __shfl_xor(a, 32, 64);
  if(lane < 16) Ein[n*ES16 + lane] = a;
  float b = 0.f;
  p1 = off[N+n+1];
  for(int p = off[N+n] + s; p < p1; p += 4) b += ev[rows[p]*ES16 + t];
  b += __shfl_xor(b, 16, 64);
  b += __shfl_xor(b, 32, 64);
  if(lane < 16) Eout[n*ES16 + lane] = b;
}

// ---------------- per-round sparse aggregation (wave per node) ----------------
__global__ void k_aggr(const float* __restrict__ h, const int* __restrict__ off,
                       const int* __restrict__ rows, const int* __restrict__ uidx,
                       const int* __restrict__ vidx,
                       float* __restrict__ Sin, float* __restrict__ Sout, int N){
  int n = (blockIdx.x*blockDim.x + threadIdx.x) >> 6;
  int lane = threadIdx.x & 63;
  if(n >= N) return;
  {
    float s = 0.f;
    int p = off[n], p1 = off[n+1];
    for(; p + 2 <= p1; p += 2){
      int e0 = rows[p], e1 = rows[p+1];
      float a = h[uidx[e0]*D64 + lane];
      float b = h[uidx[e1]*D64 + lane];
      s += a + b;
    }
    if(p < p1) s += h[uidx[rows[p]]*D64 + lane];
    Sin[n*D64 + lane] = s;
  }
  {
    float s = 0.f;
    int p = off[N+n], p1 = off[N+n+1];
    for(; p + 2 <= p1; p += 2){
      int e0 = rows[p], e1 = rows[p+1];
      float a = h[vidx[e0]*D64 + lane];
      float b = h[vidx[e1]*D64 + lane];
      s += a + b;
    }
    if(p < p1) s += h[vidx[rows[p]]*D64 + lane];
    Sout[n*D64 + lane] = s;
  }
}

// ---------------- node transform: agg = Wef*xf + Wer*xr + deg*biases ----------------
// 512 threads = 8 waves; wave wv computes jt = {wv, wv+8}.
// LDS rows: 0..63 Sin | 64..127 h | 128..191 Sout. Ein/Eout/deg read from global.
// NOTE: plain __launch_bounds__(512) — a (512,6) clamp forced VGPR=40 and ~1 GB of
// scratch spill traffic per dispatch (round-3 counters). Do not re-add.
__global__ __launch_bounds__(512) void k3_agg(
    const float* __restrict__ h, const float* __restrict__ Sin,
    const float* __restrict__ Sout, const float* __restrict__ Ein,
    const float* __restrict__ Eout, const int* __restrict__ off,
    const float* __restrict__ Wef, const float* __restrict__ bef,
    const float* __restrict__ Wer, const float* __restrict__ ber,
    float* __restrict__ aggT, int N){
  __shared__ float xT[192][67];
  const int lane = threadIdx.x & 63;
  const int wv   = threadIdx.x >> 6;
  const int base = blockIdx.x * 64;
  for(int ii = 0; ii < 8; ++ii){
    int i = wv*8 + ii;
    int n = base + i; if(n >= N) n = N - 1;
    xT[lane][i]       = Sin[n*D64 + lane];
    xT[64+lane][i]    = h[n*D64 + lane];
    xT[128+lane][i]   = Sout[n*D64 + lane];
  }
  __syncthreads();
  int node = base + lane; if(node >= N) node = N - 1;
  const float fi = (float)(off[node+1] - off[node]);
  const float fo = (float)(off[N+node+1] - off[N+node]);
  // hoisted: per-lane edge-feature sums, reused by both jt iterations
  float4 xi0 = *(const float4*)(Ein  + node*ES16 + 0);
  float4 xi1 = *(const float4*)(Ein  + node*ES16 + 4);
  float4 xi2 = *(const float4*)(Ein  + node*ES16 + 8);
  float4 xi3 = *(const float4*)(Ein  + node*ES16 + 12);
  float4 xo0 = *(const float4*)(Eout + node*ES16 + 0);
  float4 xo1 = *(const float4*)(Eout + node*ES16 + 4);
  float4 xo2 = *(const float4*)(Eout + node*ES16 + 8);
  float4 xo3 = *(const float4*)(Eout + node*ES16 + 12);
  const bool valid = (base + lane) < N;
  for(int t = 0; t < 2; ++t){
    const int jt = wv + t*8;
    float acc[8];
    #pragma unroll
    for(int jj = 0; jj < 8; ++jj){
      int j = jt*8 + jj;
      acc[jj] = fi*bef[j] + fo*ber[j];
    }
    // Sin block: Wef cols 0..63
    #pragma unroll 4
    for(int k4 = 0; k4 < 16; ++k4){
      float x0 = xT[k4*4+0][lane];
      float x1 = xT[k4*4+1][lane];
      float x2 = xT[k4*4+2][lane];
      float x3 = xT[k4*4+3][lane];
      #pragma unroll
      for(int jj = 0; jj < 8; ++jj){
        float4 w = *(const float4*)(Wef + (jt*8+jj)*144 + k4*4);
        acc[jj] = fmaf(w.x,x0,fmaf(w.y,x1,fmaf(w.z,x2,fmaf(w.w,x3,acc[jj]))));
      }
    }
    // h block: Wef cols 64..127 (×fi) and Wer cols 0..63 (×fo) share LDS reads
    #pragma unroll 2
    for(int k4 = 0; k4 < 16; ++k4){
      float h0 = xT[64+k4*4+0][lane];
      float h1 = xT[64+k4*4+1][lane];
      float h2 = xT[64+k4*4+2][lane];
      float h3 = xT[64+k4*4+3][lane];
      float f0 = fi*h0, f1 = fi*h1, f2 = fi*h2, f3 = fi*h3;
      float r0 = fo*h0, r1 = fo*h1, r2 = fo*h2, r3 = fo*h3;
      #pragma unroll
      for(int jj = 0; jj < 8; ++jj){
        int j = jt*8 + jj;
        float4 wf = *(const float4*)(Wef + j*144 + 64 + k4*4);
        float4 wr = *(const float4*)(Wer + j*144 + k4*4);
        acc[jj] = fmaf(wf.x,f0,fmaf(wf.y,f1,fmaf(wf.z,f2,fmaf(wf.w,f3,acc[jj]))));
        acc[jj] = fmaf(wr.x,r0,fmaf(wr.y,r1,fmaf(wr.z,r2,fmaf(wr.w,r3,acc[jj]))));
      }
    }
    // E blocks (register-resident)
    #pragma unroll
    for(int jj = 0; jj < 8; ++jj){
      int j = jt*8 + jj;
      const float4* wfp = (const float4*)(Wef + j*144 + 128);
      const float4* wrp = (const float4*)(Wer + j*144 + 128);
      float4 wf, wr;
      wf = wfp[0]; wr = wrp[0];
      acc[jj] = fmaf(wf.x,xi0.x,fmaf(wf.y,xi0.y,fmaf(wf.z,xi0.z,fmaf(wf.w,xi0.w,acc[jj]))));
      acc[jj] = fmaf(wr.x,xo0.x,fmaf(wr.y,xo0.y,fmaf(wr.z,xo0.z,fmaf(wr.w,xo0.w,acc[jj]))));
      wf = wfp[1]; wr = wrp[1];
      acc[jj] = fmaf(wf.x,xi1.x,fmaf(wf.y,xi1.y,fmaf(wf.z,xi1.z,fmaf(wf.w,xi1.w,acc[jj]))));
      acc[jj] = fmaf(wr.x,xo1.x,fmaf(wr.y,xo1.y,fmaf(wr.z,xo1.z,fmaf(wr.w,xo1.w,acc[jj]))));
      wf = wfp[2]; wr = wrp[2];
      acc[jj] = fmaf(wf.x,xi2.x,fmaf(wf.y,xi2.y,fmaf(wf.z,xi2.z,fmaf(wf.w,xi2.w,acc[jj]))));
      acc[jj] = fmaf(wr.x,xo2.x,fmaf(wr.y,xo2.y,fmaf(wr.z,xo2.z,fmaf(wr.w,xo2.w,acc[jj]))));
      wf = wfp[3]; wr = wrp[3];
      acc[jj] = fmaf(wf.x,xi3.x,fmaf(wf.y,xi3.y,fmaf(wf.z,xi3.z,fmaf(wf.w,xi3.w,acc[jj]))));
      acc[jj] = fmaf(wr.x,xo3.x,fmaf(wr.y,xo3.y,fmaf(wr.z,xo3.z,fmaf(wr.w,xo3.w,acc[jj]))));
    }
    // Sout block: Wer cols 64..127
    #pragma unroll 4
    for(int k4 = 0; k4 < 16; ++k4){
      float x0 = xT[128+k4*4+0][lane];
      float x1 = xT[128+k4*4+1][lane];
      float x2 = xT[128+k4*4+2][lane];
      float x3 = xT[128+k4*4+3][lane];
      #pragma unroll
      for(int jj = 0; jj < 8; ++jj){
        float4 w = *(const float4*)(Wer + (jt*8+jj)*144 + 64 + k4*4);
        acc[jj] = fmaf(w.x,x0,fmaf(w.y,x1,fmaf(w.z,x2,fmaf(w.w,x3,acc[jj]))));
      }
    }
    if(valid){
      #pragma unroll
      for(int jj = 0; jj < 8; ++jj)
        aggT[(size_t)(jt*8+jj)*N + base + lane] = acc[jj];
    }
  }
}

// ---------------- GRU: h' from aggT + h ----------------
// 512 threads = 8 waves; wave wv computes qt = wv, split in 2 halves of 4 outputs.
// xT rows 0..127 agg, 128..191 h; rows 0..63 reused as ht buffer after compute.
__global__ __launch_bounds__(512) void k4_gru(
    const float* __restrict__ hcur, const float* __restrict__ aggT,
    const float* __restrict__ Wih, const float* __restrict__ Whh,
    const float* __restrict__ bih, const float* __restrict__ bhh,
    float* __restrict__ hnext, int N){
  __shared__ float xT[192][67];
  const int lane = threadIdx.x & 63;
  const int wv   = threadIdx.x >> 6;
  const int base = blockIdx.x * 64;
  {
    int n = base + lane; if(n >= N) n = N - 1;
    for(int kk = 0; kk < 16; ++kk){
      int k = wv*16 + kk;
      xT[k][lane] = aggT[(size_t)k*N + n];
    }
  }
  for(int ii = 0; ii < 8; ++ii){
    int i = wv*8 + ii;
    int n = base + i; if(n >= N) n = N - 1;
    xT[128 + lane][i] = hcur[n*D64 + lane];
  }
  __syncthreads();
  const int qt = wv;
  float hout[8];
  #pragma unroll
  for(int half = 0; half < 2; ++half){
    float aR[4], aZ[4], aN[4], aH[4];
    #pragma unroll
    for(int i = 0; i < 4; ++i){
      int q = qt*8 + half*4 + i;
      aR[i] = bih[q]      + bhh[q];
      aZ[i] = bih[64+q]   + bhh[64+q];
      aN[i] = bih[128+q];
      aH[i] = bhh[128+q];
    }
    #pragma unroll 2
    for(int k4 = 0; k4 < 32; ++k4){
      float x0 = xT[k4*4+0][lane];
      float x1 = xT[k4*4+1][lane];
      float x2 = xT[k4*4+2][lane];
      float x3 = xT[k4*4+3][lane];
      #pragma unroll
      for(int i = 0; i < 4; ++i){
        int q = qt*8 + half*4 + i;
        float4 wr = *(const float4*)(Wih + q*128       + k4*4);
        float4 wz = *(const float4*)(Wih + (64+q)*128  + k4*4);
        float4 wn = *(const float4*)(Wih + (128+q)*128 + k4*4);
        aR[i] = fmaf(wr.x,x0,fmaf(wr.y,x1,fmaf(wr.z,x2,fmaf(wr.w,x3,aR[i]))));
        aZ[i] = fmaf(wz.x,x0,fmaf(wz.y,x1,fmaf(wz.z,x2,fmaf(wz.w,x3,aZ[i]))));
        aN[i] = fmaf(wn.x,x0,fmaf(wn.y,x1,fmaf(wn.z,x2,fmaf(wn.w,x3,aN[i]))));
      }
    }
    #pragma unroll 2
    for(int k4 = 0; k4 < 16; ++k4){
      float x0 = xT[128+k4*4+0][lane];
      float x1 = xT[128+k4*4+1][lane];
      float x2 = xT[128+k4*4+2][lane];
      float x3 = xT[128+k4*4+3][lane];
      #pragma unroll
      for(int i = 0; i < 4; ++i){
        int q = qt*8 + half*4 + i;
        float4 wr = *(const float4*)(Whh + q*64       + k4*4);
        float4 wz = *(const float4*)(Whh + (64+q)*64  + k4*4);
        float4 wh = *(const float4*)(Whh + (128+q)*64 + k4*4);
        aR[i] = fmaf(wr.x,x0,fmaf(wr.y,x1,fmaf(wr.z,x2,fmaf(wr.w,x3,aR[i]))));
        aZ[i] = fmaf(wz.x,x0,fmaf(wz.y,x1,fmaf(wz.z,x2,fmaf(wz.w,x3,aZ[i]))));
        aH[i] = fmaf(wh.x,x0,fmaf(wh.y,x1,fmaf(wh.z,x2,fmaf(wh.w,x3,aH[i]))));
      }
    }
    #pragma unroll
    for(int i = 0; i < 4; ++i){
      int q = qt*8 + half*4 + i;
      float r = sigf(aR[i]);
      float z = sigf(aZ[i]);
      float nn = tanhfast(aN[i] + r*aH[i]);
      float hq = xT[128+q][lane];
      hout[half*4 + i] = (1.f - z)*nn + z*hq;
    }
  }
  __syncthreads();   // all reads of rows 0..63 done -> safe to reuse as ht
  #pragma unroll
  for(int i = 0; i < 8; ++i){
    int q = qt*8 + i;
    xT[q][lane] = hout[i];
  }
  __syncthreads();
  for(int ii = 0; ii < 8; ++ii){
    int i = wv*8 + ii;
    int n = base + i;
    if(n < N) hnext[n*D64 + lane] = xT[lane][i];
  }
}

// ---------------- gated readout: register-accumulated partials, no atomics ----------------
__global__ __launch_bounds__(512) void k5_read(
    const float* __restrict__ h, const float* __restrict__ Wfm,
    const float* __restrict__ bfm, const float* __restrict__ Wgm,
    const float* __restrict__ bgm, float* __restrict__ partials, int N, int nT){
  __shared__ float xT[64][67];
  const int lane = threadIdx.x & 63;
  const int wv   = threadIdx.x >> 6;
  float acc[2][8];
  #pragma unroll
  for(int t = 0; t < 2; ++t)
    #pragma unroll
    for(int jj = 0; jj < 8; ++jj) acc[t][jj] = 0.f;

  for(int tile = blockIdx.x; tile < nT; tile += NB5){
    const int base = tile * 64;
    __syncthreads();
    for(int ii = 0; ii < 8; ++ii){
      int i = wv*8 + ii;
      int n = base + i; if(n >= N) n = N - 1;
      xT[lane][i] = h[n*D64 + lane];
    }
    __syncthreads();
    const bool valid = (base + lane) < N;
    for(int t = 0; t < 2; ++t){
      const int jt = wv + t*8;
      float aF[8], aG[8];
      #pragma unroll
      for(int jj = 0; jj < 8; ++jj){
        int j = jt*8 + jj;
        aF[jj] = bfm[j]; aG[jj] = bgm[j];
      }
      #pragma unroll 2
      for(int k4 = 0; k4 < 16; ++k4){
        float x0 = xT[k4*4+0][lane];
        float x1 = xT[k4*4+1][lane];
        float x2 = xT[k4*4+2][lane];
        float x3 = xT[k4*4+3][lane];
        #pragma unroll
        for(int jj = 0; jj < 8; ++jj){
          int j = jt*8 + jj;
          float4 wf = *(const float4*)(Wfm + j*64 + k4*4);
          float4 wg = *(const float4*)(Wgm + j*64 + k4*4);
          aF[jj] = fmaf(wf.x,x0,fmaf(wf.y,x1,fmaf(wf.z,x2,fmaf(wf.w,x3,aF[jj]))));
          aG[jj] = fmaf(wg.x,x0,fmaf(wg.y,x1,fmaf(wg.z,x2,fmaf(wg.w,x3,aG[jj]))));
        }
      }
      if(valid){
        #pragma unroll
        for(int jj = 0; jj < 8; ++jj)
          acc[t][jj] += aF[jj] * sigf(aG[jj]);
      }
    }
  }
  #pragma unroll
  for(int t = 0; t < 2; ++t)
    for(int jj = 0; jj < 8; ++jj){
      float val = acc[t][jj];
      #pragma unroll
      for(int o = 32; o > 0; o >>= 1) val += __shfl_xor(val, o, 64);
      if(lane == 0) partials[blockIdx.x*128 + (wv + t*8)*8 + jj] = val;
    }
}

__global__ void k6_dec(const float* __restrict__ partials, int nb,
                       const float* __restrict__ h,
                       const float* __restrict__ Wdec, const float* __restrict__ bdec,
                       const int* __restrict__ tgt, float* __restrict__ out){
  __shared__ float sm[256];
  int t = threadIdx.x;
  float v = 0.f;
  if(t < 128){
    float s0 = 0.f, s1 = 0.f, s2 = 0.f, s3 = 0.f;
    for(int b = 0; b + 4 <= nb; b += 4){
      s0 += partials[(b+0)*128 + t];
      s1 += partials[(b+1)*128 + t];
      s2 += partials[(b+2)*128 + t];
      s3 += partials[(b+3)*128 + t];
    }
    v = ((s0 + s1) + (s2 + s3)) * Wdec[t];
  } else if(t < 192){
    v = h[tgt[0]*D64 + (t - 128)] * Wdec[t];
  }
  sm[t] = v;
  __syncthreads();
  for(int s = 128; s > 0; s >>= 1){
    if(t < s) sm[t] += sm[t + s];
    __syncthreads();
  }
  if(t == 0) out[0] = sm[0] + bdec[0];
}

extern "C" void kernel_launch(void* const* d_in, const int* in_sizes, int n_in,
                              void* d_out, int out_size, void* d_ws, size_t ws_size,
                              hipStream_t stream){
  const float* nodev = (const float*)d_in[0];
  const float* ev    = (const float*)d_in[1];
  const float* Wef   = (const float*)d_in[2];
  const float* bef   = (const float*)d_in[3];
  const float* Wer   = (const float*)d_in[4];
  const float* ber   = (const float*)d_in[5];
  const float* Wih   = (const float*)d_in[6];
  const float* Whh   = (const float*)d_in[7];
  const float* bih   = (const float*)d_in[8];
  const float* bhh   = (const float*)d_in[9];
  const float* Wfm   = (const float*)d_in[10];
  const float* bfm   = (const float*)d_in[11];
  const float* Wgm   = (const float*)d_in[12];
  const float* bgm   = (const float*)d_in[13];
  const float* Wdec  = (const float*)d_in[14];
  const float* bdec  = (const float*)d_in[15];
  const int* uidx    = (const int*)d_in[16];
  const int* vidx    = (const int*)d_in[17];
  const int* tgt     = (const int*)d_in[18];

  const int N = in_sizes[0] / 64;
  const int E = in_sizes[16];
  const int R = in_sizes[2] / (128*144);

  char* w = (char*)d_ws;
  auto alloc = [&](size_t bytes) -> void* {
    void* p = (void*)w;
    w += (bytes + 255) & ~(size_t)255;
    return p;
  };
  int* off       = (int*)alloc(((size_t)2*N + 1) * 4);
  int* cur       = (int*)alloc((size_t)2*N * 4);
  int* rows      = (int*)alloc((size_t)2*E * 4);
  int* part      = (int*)alloc(4096 * 4);
  float* Ein     = (float*)alloc((size_t)N*16*4);
  float* Eout    = (float*)alloc((size_t)N*16*4);
  float* Sin     = (float*)alloc((size_t)N*64*4);
  float* Sout    = (float*)alloc((size_t)N*64*4);
  float* hA      = (float*)alloc((size_t)N*64*4);
  float* hB      = (float*)alloc((size_t)N*64*4);
  float* aggT    = (float*)alloc((size_t)128*N*4);
  float* partial = (float*)alloc((size_t)NB5*128*4);

  hipMemsetAsync(off, 0, ((size_t)2*N+1)*4, stream);

  int eb = (E + 255)/256;
  k_count<<<eb, 256, 0, stream>>>(uidx, vidx, off, N, E);
  int M = 2*N;
  int nb = (M + 255)/256;
  k_scan1<<<nb, 256, 0, stream>>>(off, part, M);
  k_scan2<<<1, 1024, 0, stream>>>(part, nb);
  k_scan3<<<nb, 256, 0, stream>>>(off, part, cur, M, 2*E);
  k_fill<<<eb, 256, 0, stream>>>(uidx, vidx, cur, rows, N, E);
  int wb = (N + 3)/4;
  k_einout<<<wb, 256, 0, stream>>>(ev, off, rows, Ein, Eout, N);

  int nT = (N + 63)/64;
  const float* hcur = nodev;
  float* bufs[2] = {hA, hB};
  for(int r = 0; r < R; ++r){
    k_aggr<<<wb, 256, 0, stream>>>(hcur, off, rows, uidx, vidx, Sin, Sout, N);
    k3_agg<<<nT, 512, 0, stream>>>(hcur, Sin, Sout, Ein, Eout, off,
                                   Wef + (size_t)r*128*144, bef + r*128,
                                   Wer + (size_t)r*128*144, ber + r*128,
                                   aggT, N);
    float* hn = bufs[r & 1];
    k4_gru<<<nT, 512, 0, stream>>>(hcur, aggT,
                                   Wih + (size_t)r*192*128, Whh + (size_t)r*192*64,
                                   bih + r*192, bhh + r*192, hn, N);
    hcur = hn;
  }
  k5_read<<<NB5, 512, 0, stream>>>(hcur, Wfm, bfm, Wgm, bgm, partial, N, nT);
  k6_dec<<<1, 256, 0, stream>>>(partial, NB5, hcur, Wdec, bdec, tgt, (float*)d_out);
}

// Round 5
// 1409.150 us; speedup vs baseline: 2.4522x; 1.7586x over previous
//
#include <hip/hip_runtime.h>
#include <math.h>

#define D64 64
#define ES16 16
#define NB5 256

__device__ __forceinline__ float sigf(float x){ return 1.0f/(1.0f + __expf(-x)); }
__device__ __forceinline__ float tanhfast(float x){ return 2.0f*sigf(2.0f*x) - 1.0f; }

// ---------------- CSR build ----------------
__global__ void k_count(const int* __restrict__ u, const int* __restrict__ v,
                        int* __restrict__ cnt, int N, int E){
  int e = blockIdx.x*256 + threadIdx.x;
  if(e < E){
    atomicAdd(&cnt[v[e]], 1);
    atomicAdd(&cnt[N + u[e]], 1);
  }
}

__global__ void k_scan1(const int* __restrict__ cnt, int* __restrict__ part, int M){
  __shared__ int sm[256];
  int i = blockIdx.x*256 + threadIdx.x;
  sm[threadIdx.x] = (i < M) ? cnt[i] : 0;
  __syncthreads();
  for(int s = 128; s > 0; s >>= 1){
    if(threadIdx.x < s) sm[threadIdx.x] += sm[threadIdx.x + s];
    __syncthreads();
  }
  if(threadIdx.x == 0) part[blockIdx.x] = sm[0];
}

__global__ void k_scan2(int* __restrict__ part, int nb){
  __shared__ int sm[1024];
  int t = threadIdx.x;
  int orig = (t < nb) ? part[t] : 0;
  sm[t] = orig;
  __syncthreads();
  for(int off = 1; off < 1024; off <<= 1){
    int add = (t >= off) ? sm[t - off] : 0;
    __syncthreads();
    sm[t] += add;
    __syncthreads();
  }
  if(t < nb) part[t] = sm[t] - orig;  // exclusive prefix
}

__global__ void k_scan3(int* __restrict__ cnt, const int* __restrict__ part,
                        int* __restrict__ cur, int M, int total){
  __shared__ int sm[256];
  int t = threadIdx.x;
  int i = blockIdx.x*256 + t;
  int orig = (i < M) ? cnt[i] : 0;
  sm[t] = orig;
  __syncthreads();
  for(int off = 1; off < 256; off <<= 1){
    int add = (t >= off) ? sm[t - off] : 0;
    __syncthreads();
    sm[t] += add;
    __syncthreads();
  }
  if(i < M){
    int excl = part[blockIdx.x] + sm[t] - orig;
    cnt[i] = excl;
    cur[i] = excl;
  }
  if(i == 0) cnt[M] = total;
}

__global__ void k_fill(const int* __restrict__ u, const int* __restrict__ v,
                       int* __restrict__ cur, int* __restrict__ rows, int N, int E){
  int e = blockIdx.x*256 + threadIdx.x;
  if(e < E){
    int p = atomicAdd(&cur[v[e]], 1); rows[p] = e;
    int q = atomicAdd(&cur[N + u[e]], 1); rows[q] = e;
  }
}

// ---------------- round-constant edge-feature sums ----------------
__global__ void k_einout(const float* __restrict__ ev, const int* __restrict__ off,
                         const int* __restrict__ rows,
                         float* __restrict__ Ein, float* __restrict__ Eout, int N){
  int n = (blockIdx.x*blockDim.x + threadIdx.x) >> 6;
  int lane = threadIdx.x & 63;
  if(n >= N) return;
  int t = lane & 15, s = lane >> 4;
  float a = 0.f;
  int p1 = off[n+1];
  for(int p = off[n] + s; p < p1; p += 4) a += ev[rows[p]*ES16 + t];
  a += __shfl_xor(a, 16, 64);
  a += __shfl_xor(a, 32, 64);
  if(lane < 16) Ein[n*ES16 + lane] = a;
  float b = 0.f;
  p1 = off[N+n+1];
  for(int p = off[N+n] + s; p < p1; p += 4) b += ev[rows[p]*ES16 + t];
  b += __shfl_xor(b, 16, 64);
  b += __shfl_xor(b, 32, 64);
  if(lane < 16) Eout[n*ES16 + lane] = b;
}

// ---------------- per-round sparse aggregation (wave per node) ----------------
__global__ void k_aggr(const float* __restrict__ h, const int* __restrict__ off,
                       const int* __restrict__ rows, const int* __restrict__ uidx,
                       const int* __restrict__ vidx,
                       float* __restrict__ Sin, float* __restrict__ Sout, int N){
  int n = (blockIdx.x*blockDim.x + threadIdx.x) >> 6;
  int lane = threadIdx.x & 63;
  if(n >= N) return;
  {
    float s = 0.f;
    int p = off[n], p1 = off[n+1];
    for(; p + 2 <= p1; p += 2){
      int e0 = rows[p], e1 = rows[p+1];
      float a = h[uidx[e0]*D64 + lane];
      float b = h[uidx[e1]*D64 + lane];
      s += a + b;
    }
    if(p < p1) s += h[uidx[rows[p]]*D64 + lane];
    Sin[n*D64 + lane] = s;
  }
  {
    float s = 0.f;
    int p = off[N+n], p1 = off[N+n+1];
    for(; p + 2 <= p1; p += 2){
      int e0 = rows[p], e1 = rows[p+1];
      float a = h[vidx[e0]*D64 + lane];
      float b = h[vidx[e1]*D64 + lane];
      s += a + b;
    }
    if(p < p1) s += h[vidx[rows[p]]*D64 + lane];
    Sout[n*D64 + lane] = s;
  }
}

// ---------------- node transform: agg = Wef*xf + Wer*xr + deg*biases ----------------
// 512 threads = 8 waves; wave wv computes jt = {wv, wv+8}.
// wv is forced wave-uniform via readfirstlane so ALL weight/bias addresses are
// scalar -> compiler emits s_load through the constant cache (SGPR operands),
// removing ~1150 per-lane VMEM loads/wave that kept VALUBusy at 24% (round-4).
// NOTE: plain __launch_bounds__(512) — a (512,6) clamp forced VGPR=40 and ~1 GB of
// scratch spill traffic per dispatch (round-3 counters). Do not re-add.
__global__ __launch_bounds__(512) void k3_agg(
    const float* __restrict__ h, const float* __restrict__ Sin,
    const float* __restrict__ Sout, const float* __restrict__ Ein,
    const float* __restrict__ Eout, const int* __restrict__ off,
    const float* __restrict__ Wef, const float* __restrict__ bef,
    const float* __restrict__ Wer, const float* __restrict__ ber,
    float* __restrict__ aggT, int N){
  __shared__ float xT[192][67];
  const int lane = threadIdx.x & 63;
  const int wv   = __builtin_amdgcn_readfirstlane(threadIdx.x >> 6);
  const int base = blockIdx.x * 64;
  for(int ii = 0; ii < 8; ++ii){
    int i = wv*8 + ii;
    int n = base + i; if(n >= N) n = N - 1;
    xT[lane][i]       = Sin[n*D64 + lane];
    xT[64+lane][i]    = h[n*D64 + lane];
    xT[128+lane][i]   = Sout[n*D64 + lane];
  }
  __syncthreads();
  int node = base + lane; if(node >= N) node = N - 1;
  const float fi = (float)(off[node+1] - off[node]);
  const float fo = (float)(off[N+node+1] - off[N+node]);
  // hoisted: per-lane edge-feature sums, reused by both jt iterations
  float4 xi0 = *(const float4*)(Ein  + node*ES16 + 0);
  float4 xi1 = *(const float4*)(Ein  + node*ES16 + 4);
  float4 xi2 = *(const float4*)(Ein  + node*ES16 + 8);
  float4 xi3 = *(const float4*)(Ein  + node*ES16 + 12);
  float4 xo0 = *(const float4*)(Eout + node*ES16 + 0);
  float4 xo1 = *(const float4*)(Eout + node*ES16 + 4);
  float4 xo2 = *(const float4*)(Eout + node*ES16 + 8);
  float4 xo3 = *(const float4*)(Eout + node*ES16 + 12);
  const bool valid = (base + lane) < N;
  for(int t = 0; t < 2; ++t){
    const int jt = wv + t*8;
    float acc[8];
    #pragma unroll
    for(int jj = 0; jj < 8; ++jj){
      int j = jt*8 + jj;
      acc[jj] = fi*bef[j] + fo*ber[j];
    }
    // Sin block: Wef cols 0..63
    #pragma unroll 4
    for(int k4 = 0; k4 < 16; ++k4){
      float x0 = xT[k4*4+0][lane];
      float x1 = xT[k4*4+1][lane];
      float x2 = xT[k4*4+2][lane];
      float x3 = xT[k4*4+3][lane];
      #pragma unroll
      for(int jj = 0; jj < 8; ++jj){
        float4 w = *(const float4*)(Wef + (jt*8+jj)*144 + k4*4);
        acc[jj] = fmaf(w.x,x0,fmaf(w.y,x1,fmaf(w.z,x2,fmaf(w.w,x3,acc[jj]))));
      }
    }
    // h block: Wef cols 64..127 (×fi) and Wer cols 0..63 (×fo) share LDS reads
    #pragma unroll 2
    for(int k4 = 0; k4 < 16; ++k4){
      float h0 = xT[64+k4*4+0][lane];
      float h1 = xT[64+k4*4+1][lane];
      float h2 = xT[64+k4*4+2][lane];
      float h3 = xT[64+k4*4+3][lane];
      float f0 = fi*h0, f1 = fi*h1, f2 = fi*h2, f3 = fi*h3;
      float r0 = fo*h0, r1 = fo*h1, r2 = fo*h2, r3 = fo*h3;
      #pragma unroll
      for(int jj = 0; jj < 8; ++jj){
        int j = jt*8 + jj;
        float4 wf = *(const float4*)(Wef + j*144 + 64 + k4*4);
        float4 wr = *(const float4*)(Wer + j*144 + k4*4);
        acc[jj] = fmaf(wf.x,f0,fmaf(wf.y,f1,fmaf(wf.z,f2,fmaf(wf.w,f3,acc[jj]))));
        acc[jj] = fmaf(wr.x,r0,fmaf(wr.y,r1,fmaf(wr.z,r2,fmaf(wr.w,r3,acc[jj]))));
      }
    }
    // E blocks (register-resident x, scalar weights)
    #pragma unroll
    for(int jj = 0; jj < 8; ++jj){
      int j = jt*8 + jj;
      const float4* wfp = (const float4*)(Wef + j*144 + 128);
      const float4* wrp = (const float4*)(Wer + j*144 + 128);
      float4 wf, wr;
      wf = wfp[0]; wr = wrp[0];
      acc[jj] = fmaf(wf.x,xi0.x,fmaf(wf.y,xi0.y,fmaf(wf.z,xi0.z,fmaf(wf.w,xi0.w,acc[jj]))));
      acc[jj] = fmaf(wr.x,xo0.x,fmaf(wr.y,xo0.y,fmaf(wr.z,xo0.z,fmaf(wr.w,xo0.w,acc[jj]))));
      wf = wfp[1]; wr = wrp[1];
      acc[jj] = fmaf(wf.x,xi1.x,fmaf(wf.y,xi1.y,fmaf(wf.z,xi1.z,fmaf(wf.w,xi1.w,acc[jj]))));
      acc[jj] = fmaf(wr.x,xo1.x,fmaf(wr.y,xo1.y,fmaf(wr.z,xo1.z,fmaf(wr.w,xo1.w,acc[jj]))));
      wf = wfp[2]; wr = wrp[2];
      acc[jj] = fmaf(wf.x,xi2.x,fmaf(wf.y,xi2.y,fmaf(wf.z,xi2.z,fmaf(wf.w,xi2.w,acc[jj]))));
      acc[jj] = fmaf(wr.x,xo2.x,fmaf(wr.y,xo2.y,fmaf(wr.z,xo2.z,fmaf(wr.w,xo2.w,acc[jj]))));
      wf = wfp[3]; wr = wrp[3];
      acc[jj] = fmaf(wf.x,xi3.x,fmaf(wf.y,xi3.y,fmaf(wf.z,xi3.z,fmaf(wf.w,xi3.w,acc[jj]))));
      acc[jj] = fmaf(wr.x,xo3.x,fmaf(wr.y,xo3.y,fmaf(wr.z,xo3.z,fmaf(wr.w,xo3.w,acc[jj]))));
    }
    // Sout block: Wer cols 64..127
    #pragma unroll 4
    for(int k4 = 0; k4 < 16; ++k4){
      float x0 = xT[128+k4*4+0][lane];
      float x1 = xT[128+k4*4+1][lane];
      float x2 = xT[128+k4*4+2][lane];
      float x3 = xT[128+k4*4+3][lane];
      #pragma unroll
      for(int jj = 0; jj < 8; ++jj){
        float4 w = *(const float4*)(Wer + (jt*8+jj)*144 + 64 + k4*4);
        acc[jj] = fmaf(w.x,x0,fmaf(w.y,x1,fmaf(w.z,x2,fmaf(w.w,x3,acc[jj]))));
      }
    }
    if(valid){
      #pragma unroll
      for(int jj = 0; jj < 8; ++jj)
        aggT[(size_t)(jt*8+jj)*N + base + lane] = acc[jj];
    }
  }
}

// ---------------- GRU: h' from aggT + h ----------------
// 512 threads = 8 waves; wave wv computes qt = wv (uniform via readfirstlane ->
// scalar weight loads), split in 2 halves of 4 outputs.
// xT rows 0..127 agg, 128..191 h; rows 0..63 reused as ht buffer after compute.
__global__ __launch_bounds__(512) void k4_gru(
    const float* __restrict__ hcur, const float* __restrict__ aggT,
    const float* __restrict__ Wih, const float* __restrict__ Whh,
    const float* __restrict__ bih, const float* __restrict__ bhh,
    float* __restrict__ hnext, int N){
  __shared__ float xT[192][67];
  const int lane = threadIdx.x & 63;
  const int wv   = __builtin_amdgcn_readfirstlane(threadIdx.x >> 6);
  const int base = blockIdx.x * 64;
  {
    int n = base + lane; if(n >= N) n = N - 1;
    for(int kk = 0; kk < 16; ++kk){
      int k = wv*16 + kk;
      xT[k][lane] = aggT[(size_t)k*N + n];
    }
  }
  for(int ii = 0; ii < 8; ++ii){
    int i = wv*8 + ii;
    int n = base + i; if(n >= N) n = N - 1;
    xT[128 + lane][i] = hcur[n*D64 + lane];
  }
  __syncthreads();
  const int qt = wv;
  float hout[8];
  #pragma unroll
  for(int half = 0; half < 2; ++half){
    float aR[4], aZ[4], aN[4], aH[4];
    #pragma unroll
    for(int i = 0; i < 4; ++i){
      int q = qt*8 + half*4 + i;
      aR[i] = bih[q]      + bhh[q];
      aZ[i] = bih[64+q]   + bhh[64+q];
      aN[i] = bih[128+q];
      aH[i] = bhh[128+q];
    }
    #pragma unroll 2
    for(int k4 = 0; k4 < 32; ++k4){
      float x0 = xT[k4*4+0][lane];
      float x1 = xT[k4*4+1][lane];
      float x2 = xT[k4*4+2][lane];
      float x3 = xT[k4*4+3][lane];
      #pragma unroll
      for(int i = 0; i < 4; ++i){
        int q = qt*8 + half*4 + i;
        float4 wr = *(const float4*)(Wih + q*128       + k4*4);
        float4 wz = *(const float4*)(Wih + (64+q)*128  + k4*4);
        float4 wn = *(const float4*)(Wih + (128+q)*128 + k4*4);
        aR[i] = fmaf(wr.x,x0,fmaf(wr.y,x1,fmaf(wr.z,x2,fmaf(wr.w,x3,aR[i]))));
        aZ[i] = fmaf(wz.x,x0,fmaf(wz.y,x1,fmaf(wz.z,x2,fmaf(wz.w,x3,aZ[i]))));
        aN[i] = fmaf(wn.x,x0,fmaf(wn.y,x1,fmaf(wn.z,x2,fmaf(wn.w,x3,aN[i]))));
      }
    }
    #pragma unroll 2
    for(int k4 = 0; k4 < 16; ++k4){
      float x0 = xT[128+k4*4+0][lane];
      float x1 = xT[128+k4*4+1][lane];
      float x2 = xT[128+k4*4+2][lane];
      float x3 = xT[128+k4*4+3][lane];
      #pragma unroll
      for(int i = 0; i < 4; ++i){
        int q = qt*8 + half*4 + i;
        float4 wr = *(const float4*)(Whh + q*64       + k4*4);
        float4 wz = *(const float4*)(Whh + (64+q)*64  + k4*4);
        float4 wh = *(const float4*)(Whh + (128+q)*64 + k4*4);
        aR[i] = fmaf(wr.x,x0,fmaf(wr.y,x1,fmaf(wr.z,x2,fmaf(wr.w,x3,aR[i]))));
        aZ[i] = fmaf(wz.x,x0,fmaf(wz.y,x1,fmaf(wz.z,x2,fmaf(wz.w,x3,aZ[i]))));
        aH[i] = fmaf(wh.x,x0,fmaf(wh.y,x1,fmaf(wh.z,x2,fmaf(wh.w,x3,aH[i]))));
      }
    }
    #pragma unroll
    for(int i = 0; i < 4; ++i){
      int q = qt*8 + half*4 + i;
      float r = sigf(aR[i]);
      float z = sigf(aZ[i]);
      float nn = tanhfast(aN[i] + r*aH[i]);
      float hq = xT[128+q][lane];
      hout[half*4 + i] = (1.f - z)*nn + z*hq;
    }
  }
  __syncthreads();   // all reads of rows 0..63 done -> safe to reuse as ht
  #pragma unroll
  for(int i = 0; i < 8; ++i){
    int q = qt*8 + i;
    xT[q][lane] = hout[i];
  }
  __syncthreads();
  for(int ii = 0; ii < 8; ++ii){
    int i = wv*8 + ii;
    int n = base + i;
    if(n < N) hnext[n*D64 + lane] = xT[lane][i];
  }
}

// ---------------- gated readout: register-accumulated partials, no atomics ----------------
__global__ __launch_bounds__(512) void k5_read(
    const float* __restrict__ h, const float* __restrict__ Wfm,
    const float* __restrict__ bfm, const float* __restrict__ Wgm,
    const float* __restrict__ bgm, float* __restrict__ partials, int N, int nT){
  __shared__ float xT[64][67];
  const int lane = threadIdx.x & 63;
  const int wv   = __builtin_amdgcn_readfirstlane(threadIdx.x >> 6);
  float acc[2][8];
  #pragma unroll
  for(int t = 0; t < 2; ++t)
    #pragma unroll
    for(int jj = 0; jj < 8; ++jj) acc[t][jj] = 0.f;

  for(int tile = blockIdx.x; tile < nT; tile += NB5){
    const int base = tile * 64;
    __syncthreads();
    for(int ii = 0; ii < 8; ++ii){
      int i = wv*8 + ii;
      int n = base + i; if(n >= N) n = N - 1;
      xT[lane][i] = h[n*D64 + lane];
    }
    __syncthreads();
    const bool valid = (base + lane) < N;
    for(int t = 0; t < 2; ++t){
      const int jt = wv + t*8;
      float aF[8], aG[8];
      #pragma unroll
      for(int jj = 0; jj < 8; ++jj){
        int j = jt*8 + jj;
        aF[jj] = bfm[j]; aG[jj] = bgm[j];
      }
      #pragma unroll 2
      for(int k4 = 0; k4 < 16; ++k4){
        float x0 = xT[k4*4+0][lane];
        float x1 = xT[k4*4+1][lane];
        float x2 = xT[k4*4+2][lane];
        float x3 = xT[k4*4+3][lane];
        #pragma unroll
        for(int jj = 0; jj < 8; ++jj){
          int j = jt*8 + jj;
          float4 wf = *(const float4*)(Wfm + j*64 + k4*4);
          float4 wg = *(const float4*)(Wgm + j*64 + k4*4);
          aF[jj] = fmaf(wf.x,x0,fmaf(wf.y,x1,fmaf(wf.z,x2,fmaf(wf.w,x3,aF[jj]))));
          aG[jj] = fmaf(wg.x,x0,fmaf(wg.y,x1,fmaf(wg.z,x2,fmaf(wg.w,x3,aG[jj]))));
        }
      }
      if(valid){
        #pragma unroll
        for(int jj = 0; jj < 8; ++jj)
          acc[t][jj] += aF[jj] * sigf(aG[jj]);
      }
    }
  }
  #pragma unroll
  for(int t = 0; t < 2; ++t)
    for(int jj = 0; jj < 8; ++jj){
      float val = acc[t][jj];
      #pragma unroll
      for(int o = 32; o > 0; o >>= 1) val += __shfl_xor(val, o, 64);
      if(lane == 0) partials[blockIdx.x*128 + (wv + t*8)*8 + jj] = val;
    }
}

__global__ void k6_dec(const float* __restrict__ partials, int nb,
                       const float* __restrict__ h,
                       const float* __restrict__ Wdec, const float* __restrict__ bdec,
                       const int* __restrict__ tgt, float* __restrict__ out){
  __shared__ float sm[256];
  int t = threadIdx.x;
  float v = 0.f;
  if(t < 128){
    float s0 = 0.f, s1 = 0.f, s2 = 0.f, s3 = 0.f;
    for(int b = 0; b + 4 <= nb; b += 4){
      s0 += partials[(b+0)*128 + t];
      s1 += partials[(b+1)*128 + t];
      s2 += partials[(b+2)*128 + t];
      s3 += partials[(b+3)*128 + t];
    }
    v = ((s0 + s1) + (s2 + s3)) * Wdec[t];
  } else if(t < 192){
    v = h[tgt[0]*D64 + (t - 128)] * Wdec[t];
  }
  sm[t] = v;
  __syncthreads();
  for(int s = 128; s > 0; s >>= 1){
    if(t < s) sm[t] += sm[t + s];
    __syncthreads();
  }
  if(t == 0) out[0] = sm[0] + bdec[0];
}

extern "C" void kernel_launch(void* const* d_in, const int* in_sizes, int n_in,
                              void* d_out, int out_size, void* d_ws, size_t ws_size,
                              hipStream_t stream){
  const float* nodev = (const float*)d_in[0];
  const float* ev    = (const float*)d_in[1];
  const float* Wef   = (const float*)d_in[2];
  const float* bef   = (const float*)d_in[3];
  const float* Wer   = (const float*)d_in[4];
  const float* ber   = (const float*)d_in[5];
  const float* Wih   = (const float*)d_in[6];
  const float* Whh   = (const float*)d_in[7];
  const float* bih   = (const float*)d_in[8];
  const float* bhh   = (const float*)d_in[9];
  const float* Wfm   = (const float*)d_in[10];
  const float* bfm   = (const float*)d_in[11];
  const float* Wgm   = (const float*)d_in[12];
  const float* bgm   = (const float*)d_in[13];
  const float* Wdec  = (const float*)d_in[14];
  const float* bdec  = (const float*)d_in[15];
  const int* uidx    = (const int*)d_in[16];
  const int* vidx    = (const int*)d_in[17];
  const int* tgt     = (const int*)d_in[18];

  const int N = in_sizes[0] / 64;
  const int E = in_sizes[16];
  const int R = in_sizes[2] / (128*144);

  char* w = (char*)d_ws;
  auto alloc = [&](size_t bytes) -> void* {
    void* p = (void*)w;
    w += (bytes + 255) & ~(size_t)255;
    return p;
  };
  int* off       = (int*)alloc(((size_t)2*N + 1) * 4);
  int* cur       = (int*)alloc((size_t)2*N * 4);
  int* rows      = (int*)alloc((size_t)2*E * 4);
  int* part      = (int*)alloc(4096 * 4);
  float* Ein     = (float*)alloc((size_t)N*16*4);
  float* Eout    = (float*)alloc((size_t)N*16*4);
  float* Sin     = (float*)alloc((size_t)N*64*4);
  float* Sout    = (float*)alloc((size_t)N*64*4);
  float* hA      = (float*)alloc((size_t)N*64*4);
  float* hB      = (float*)alloc((size_t)N*64*4);
  float* aggT    = (float*)alloc((size_t)128*N*4);
  float* partial = (float*)alloc((size_t)NB5*128*4);

  hipMemsetAsync(off, 0, ((size_t)2*N+1)*4, stream);

  int eb = (E + 255)/256;
  k_count<<<eb, 256, 0, stream>>>(uidx, vidx, off, N, E);
  int M = 2*N;
  int nb = (M + 255)/256;
  k_scan1<<<nb, 256, 0, stream>>>(off, part, M);
  k_scan2<<<1, 1024, 0, stream>>>(part, nb);
  k_scan3<<<nb, 256, 0, stream>>>(off, part, cur, M, 2*E);
  k_fill<<<eb, 256, 0, stream>>>(uidx, vidx, cur, rows, N, E);
  int wb = (N + 3)/4;
  k_einout<<<wb, 256, 0, stream>>>(ev, off, rows, Ein, Eout, N);

  int nT = (N + 63)/64;
  const float* hcur = nodev;
  float* bufs[2] = {hA, hB};
  for(int r = 0; r < R; ++r){
    k_aggr<<<wb, 256, 0, stream>>>(hcur, off, rows, uidx, vidx, Sin, Sout, N);
    k3_agg<<<nT, 512, 0, stream>>>(hcur, Sin, Sout, Ein, Eout, off,
                                   Wef + (size_t)r*128*144, bef + r*128,
                                   Wer + (size_t)r*128*144, ber + r*128,
                                   aggT, N);
    float* hn = bufs[r & 1];
    k4_gru<<<nT, 512, 0, stream>>>(hcur, aggT,
                                   Wih + (size_t)r*192*128, Whh + (size_t)r*192*64,
                                   bih + r*192, bhh + r*192, hn, N);
    hcur = hn;
  }
  k5_read<<<NB5, 512, 0, stream>>>(hcur, Wfm, bfm, Wgm, bgm, partial, N, nT);
  k6_dec<<<1, 256, 0, stream>>>(partial, NB5, hcur, Wdec, bdec, tgt, (float*)d_out);
}

// Round 6
// 1392.730 us; speedup vs baseline: 2.4811x; 1.0118x over previous
//
#include <hip/hip_runtime.h>
#include <math.h>

#define D64 64
#define ES16 16
#define NB5 256

__device__ __forceinline__ float sigf(float x){ return 1.0f/(1.0f + __expf(-x)); }
__device__ __forceinline__ float tanhfast(float x){ return 2.0f*sigf(2.0f*x) - 1.0f; }

// ---------------- CSR build ----------------
__global__ void k_count(const int* __restrict__ u, const int* __restrict__ v,
                        int* __restrict__ cnt, int N, int E){
  int e = blockIdx.x*256 + threadIdx.x;
  if(e < E){
    atomicAdd(&cnt[v[e]], 1);
    atomicAdd(&cnt[N + u[e]], 1);
  }
}

__global__ void k_scan1(const int* __restrict__ cnt, int* __restrict__ part, int M){
  __shared__ int sm[256];
  int i = blockIdx.x*256 + threadIdx.x;
  sm[threadIdx.x] = (i < M) ? cnt[i] : 0;
  __syncthreads();
  for(int s = 128; s > 0; s >>= 1){
    if(threadIdx.x < s) sm[threadIdx.x] += sm[threadIdx.x + s];
    __syncthreads();
  }
  if(threadIdx.x == 0) part[blockIdx.x] = sm[0];
}

__global__ void k_scan2(int* __restrict__ part, int nb){
  __shared__ int sm[1024];
  int t = threadIdx.x;
  int orig = (t < nb) ? part[t] : 0;
  sm[t] = orig;
  __syncthreads();
  for(int off = 1; off < 1024; off <<= 1){
    int add = (t >= off) ? sm[t - off] : 0;
    __syncthreads();
    sm[t] += add;
    __syncthreads();
  }
  if(t < nb) part[t] = sm[t] - orig;  // exclusive prefix
}

__global__ void k_scan3(int* __restrict__ cnt, const int* __restrict__ part,
                        int* __restrict__ cur, int M, int total){
  __shared__ int sm[256];
  int t = threadIdx.x;
  int i = blockIdx.x*256 + t;
  int orig = (i < M) ? cnt[i] : 0;
  sm[t] = orig;
  __syncthreads();
  for(int off = 1; off < 256; off <<= 1){
    int add = (t >= off) ? sm[t - off] : 0;
    __syncthreads();
    sm[t] += add;
    __syncthreads();
  }
  if(i < M){
    int excl = part[blockIdx.x] + sm[t] - orig;
    cnt[i] = excl;
    cur[i] = excl;
  }
  if(i == 0) cnt[M] = total;
}

__global__ void k_fill(const int* __restrict__ u, const int* __restrict__ v,
                       int* __restrict__ cur, int* __restrict__ rows, int N, int E){
  int e = blockIdx.x*256 + threadIdx.x;
  if(e < E){
    int p = atomicAdd(&cur[v[e]], 1); rows[p] = e;
    int q = atomicAdd(&cur[N + u[e]], 1); rows[q] = e;
  }
}

// ---------------- round-constant edge-feature sums ----------------
__global__ void k_einout(const float* __restrict__ ev, const int* __restrict__ off,
                         const int* __restrict__ rows,
                         float* __restrict__ Ein, float* __restrict__ Eout, int N){
  int n = (blockIdx.x*blockDim.x + threadIdx.x) >> 6;
  int lane = threadIdx.x & 63;
  if(n >= N) return;
  int t = lane & 15, s = lane >> 4;
  float a = 0.f;
  int p1 = off[n+1];
  for(int p = off[n] + s; p < p1; p += 4) a += ev[rows[p]*ES16 + t];
  a += __shfl_xor(a, 16, 64);
  a += __shfl_xor(a, 32, 64);
  if(lane < 16) Ein[n*ES16 + lane] = a;
  float b = 0.f;
  p1 = off[N+n+1];
  for(int p = off[N+n] + s; p < p1; p += 4) b += ev[rows[p]*ES16 + t];
  b += __shfl_xor(b, 16, 64);
  b += __shfl_xor(b, 32, 64);
  if(lane < 16) Eout[n*ES16 + lane] = b;
}

// ---------------- per-round sparse aggregation (wave per node) ----------------
__global__ void k_aggr(const float* __restrict__ h, const int* __restrict__ off,
                       const int* __restrict__ rows, const int* __restrict__ uidx,
                       const int* __restrict__ vidx,
                       float* __restrict__ Sin, float* __restrict__ Sout, int N){
  int n = (blockIdx.x*blockDim.x + threadIdx.x) >> 6;
  int lane = threadIdx.x & 63;
  if(n >= N) return;
  {
    float s = 0.f;
    int p = off[n], p1 = off[n+1];
    for(; p + 2 <= p1; p += 2){
      int e0 = rows[p], e1 = rows[p+1];
      float a = h[uidx[e0]*D64 + lane];
      float b = h[uidx[e1]*D64 + lane];
      s += a + b;
    }
    if(p < p1) s += h[uidx[rows[p]]*D64 + lane];
    Sin[n*D64 + lane] = s;
  }
  {
    float s = 0.f;
    int p = off[N+n], p1 = off[N+n+1];
    for(; p + 2 <= p1; p += 2){
      int e0 = rows[p], e1 = rows[p+1];
      float a = h[vidx[e0]*D64 + lane];
      float b = h[vidx[e1]*D64 + lane];
      s += a + b;
    }
    if(p < p1) s += h[vidx[rows[p]]*D64 + lane];
    Sout[n*D64 + lane] = s;
  }
}

// ---------------- fused node transform + GRU ----------------
// 512 threads = 8 waves per 64-node tile.
// Phase A (= old k3): wave wv computes agg cols {wv*8..wv*8+7} (t=0) and
// {64+wv*8..64+wv*8+7} (t=1) for all 64 nodes.
// Then agg is written into the dead Sin/Sout LDS rows (col c<64 -> row c,
// c>=64 -> row 128+(c-64)); h stays at rows 64..127.
// Phase B (= old k4): GRU in-place. Eliminates the 25.6MB aggT write+read and
// k4's global restaging entirely.
// wv is wave-uniform via readfirstlane -> weight/bias loads are s_load (SGPR).
// NOTE: plain __launch_bounds__(512) — a (512,6) clamp forced VGPR=40 and ~1 GB
// of scratch spill per dispatch (round-3 counters). Do not re-add.
__global__ __launch_bounds__(512) void k34_fused(
    const float* __restrict__ h, const float* __restrict__ Sin,
    const float* __restrict__ Sout, const float* __restrict__ Ein,
    const float* __restrict__ Eout, const int* __restrict__ off,
    const float* __restrict__ Wef, const float* __restrict__ bef,
    const float* __restrict__ Wer, const float* __restrict__ ber,
    const float* __restrict__ Wih, const float* __restrict__ Whh,
    const float* __restrict__ bih, const float* __restrict__ bhh,
    float* __restrict__ hnext, int N){
  __shared__ float xT[192][67];
  const int lane = threadIdx.x & 63;
  const int wv   = __builtin_amdgcn_readfirstlane(threadIdx.x >> 6);
  const int base = blockIdx.x * 64;
  for(int ii = 0; ii < 8; ++ii){
    int i = wv*8 + ii;
    int n = base + i; if(n >= N) n = N - 1;
    xT[lane][i]       = Sin[n*D64 + lane];
    xT[64+lane][i]    = h[n*D64 + lane];
    xT[128+lane][i]   = Sout[n*D64 + lane];
  }
  __syncthreads();
  int node = base + lane; if(node >= N) node = N - 1;
  const float fi = (float)(off[node+1] - off[node]);
  const float fo = (float)(off[N+node+1] - off[N+node]);
  // hoisted per-lane edge-feature sums, reused by both jt iterations
  float4 xi0 = *(const float4*)(Ein  + node*ES16 + 0);
  float4 xi1 = *(const float4*)(Ein  + node*ES16 + 4);
  float4 xi2 = *(const float4*)(Ein  + node*ES16 + 8);
  float4 xi3 = *(const float4*)(Ein  + node*ES16 + 12);
  float4 xo0 = *(const float4*)(Eout + node*ES16 + 0);
  float4 xo1 = *(const float4*)(Eout + node*ES16 + 4);
  float4 xo2 = *(const float4*)(Eout + node*ES16 + 8);
  float4 xo3 = *(const float4*)(Eout + node*ES16 + 12);
  const bool valid = (base + lane) < N;

  float agg[2][8];   // keep both jt results until all waves finish reading LDS
  for(int t = 0; t < 2; ++t){
    const int jt = wv + t*8;
    float acc[8];
    #pragma unroll
    for(int jj = 0; jj < 8; ++jj){
      int j = jt*8 + jj;
      acc[jj] = fi*bef[j] + fo*ber[j];
    }
    // Sin block: Wef cols 0..63
    #pragma unroll 4
    for(int k4 = 0; k4 < 16; ++k4){
      float x0 = xT[k4*4+0][lane];
      float x1 = xT[k4*4+1][lane];
      float x2 = xT[k4*4+2][lane];
      float x3 = xT[k4*4+3][lane];
      #pragma unroll
      for(int jj = 0; jj < 8; ++jj){
        float4 w = *(const float4*)(Wef + (jt*8+jj)*144 + k4*4);
        acc[jj] = fmaf(w.x,x0,fmaf(w.y,x1,fmaf(w.z,x2,fmaf(w.w,x3,acc[jj]))));
      }
    }
    // h block: Wef cols 64..127 (×fi) and Wer cols 0..63 (×fo) share LDS reads
    #pragma unroll 2
    for(int k4 = 0; k4 < 16; ++k4){
      float h0 = xT[64+k4*4+0][lane];
      float h1 = xT[64+k4*4+1][lane];
      float h2 = xT[64+k4*4+2][lane];
      float h3 = xT[64+k4*4+3][lane];
      float f0 = fi*h0, f1 = fi*h1, f2 = fi*h2, f3 = fi*h3;
      float r0 = fo*h0, r1 = fo*h1, r2 = fo*h2, r3 = fo*h3;
      #pragma unroll
      for(int jj = 0; jj < 8; ++jj){
        int j = jt*8 + jj;
        float4 wf = *(const float4*)(Wef + j*144 + 64 + k4*4);
        float4 wr = *(const float4*)(Wer + j*144 + k4*4);
        acc[jj] = fmaf(wf.x,f0,fmaf(wf.y,f1,fmaf(wf.z,f2,fmaf(wf.w,f3,acc[jj]))));
        acc[jj] = fmaf(wr.x,r0,fmaf(wr.y,r1,fmaf(wr.z,r2,fmaf(wr.w,r3,acc[jj]))));
      }
    }
    // E blocks (register-resident x, scalar weights)
    #pragma unroll
    for(int jj = 0; jj < 8; ++jj){
      int j = jt*8 + jj;
      const float4* wfp = (const float4*)(Wef + j*144 + 128);
      const float4* wrp = (const float4*)(Wer + j*144 + 128);
      float4 wf, wr;
      wf = wfp[0]; wr = wrp[0];
      acc[jj] = fmaf(wf.x,xi0.x,fmaf(wf.y,xi0.y,fmaf(wf.z,xi0.z,fmaf(wf.w,xi0.w,acc[jj]))));
      acc[jj] = fmaf(wr.x,xo0.x,fmaf(wr.y,xo0.y,fmaf(wr.z,xo0.z,fmaf(wr.w,xo0.w,acc[jj]))));
      wf = wfp[1]; wr = wrp[1];
      acc[jj] = fmaf(wf.x,xi1.x,fmaf(wf.y,xi1.y,fmaf(wf.z,xi1.z,fmaf(wf.w,xi1.w,acc[jj]))));
      acc[jj] = fmaf(wr.x,xo1.x,fmaf(wr.y,xo1.y,fmaf(wr.z,xo1.z,fmaf(wr.w,xo1.w,acc[jj]))));
      wf = wfp[2]; wr = wrp[2];
      acc[jj] = fmaf(wf.x,xi2.x,fmaf(wf.y,xi2.y,fmaf(wf.z,xi2.z,fmaf(wf.w,xi2.w,acc[jj]))));
      acc[jj] = fmaf(wr.x,xo2.x,fmaf(wr.y,xo2.y,fmaf(wr.z,xo2.z,fmaf(wr.w,xo2.w,acc[jj]))));
      wf = wfp[3]; wr = wrp[3];
      acc[jj] = fmaf(wf.x,xi3.x,fmaf(wf.y,xi3.y,fmaf(wf.z,xi3.z,fmaf(wf.w,xi3.w,acc[jj]))));
      acc[jj] = fmaf(wr.x,xo3.x,fmaf(wr.y,xo3.y,fmaf(wr.z,xo3.z,fmaf(wr.w,xo3.w,acc[jj]))));
    }
    // Sout block: Wer cols 64..127
    #pragma unroll 4
    for(int k4 = 0; k4 < 16; ++k4){
      float x0 = xT[128+k4*4+0][lane];
      float x1 = xT[128+k4*4+1][lane];
      float x2 = xT[128+k4*4+2][lane];
      float x3 = xT[128+k4*4+3][lane];
      #pragma unroll
      for(int jj = 0; jj < 8; ++jj){
        float4 w = *(const float4*)(Wer + (jt*8+jj)*144 + 64 + k4*4);
        acc[jj] = fmaf(w.x,x0,fmaf(w.y,x1,fmaf(w.z,x2,fmaf(w.w,x3,acc[jj]))));
      }
    }
    #pragma unroll
    for(int jj = 0; jj < 8; ++jj) agg[t][jj] = acc[jj];
  }

  // ---- agg -> LDS (reuse Sin/Sout rows); h rows 64..127 stay live ----
  __syncthreads();   // all waves done READING Sin/Sout rows
  #pragma unroll
  for(int jj = 0; jj < 8; ++jj){
    xT[wv*8 + jj][lane]       = agg[0][jj];   // agg cols 0..63   -> rows 0..63
    xT[128 + wv*8 + jj][lane] = agg[1][jj];   // agg cols 64..127 -> rows 128..191
  }
  __syncthreads();

  // ---- Phase B: GRU. agg dim k<64 -> row k; k>=64 -> row 128+(k-64); h -> 64+k.
  const int qt = wv;
  float hout[8];
  #pragma unroll
  for(int half = 0; half < 2; ++half){
    float aR[4], aZ[4], aN[4], aH[4];
    #pragma unroll
    for(int i = 0; i < 4; ++i){
      int q = qt*8 + half*4 + i;
      aR[i] = bih[q]      + bhh[q];
      aZ[i] = bih[64+q]   + bhh[64+q];
      aN[i] = bih[128+q];
      aH[i] = bhh[128+q];
    }
    // W_ih x agg, k = 0..63 (rows 0..63)
    #pragma unroll 2
    for(int k4 = 0; k4 < 16; ++k4){
      float x0 = xT[k4*4+0][lane];
      float x1 = xT[k4*4+1][lane];
      float x2 = xT[k4*4+2][lane];
      float x3 = xT[k4*4+3][lane];
      #pragma unroll
      for(int i = 0; i < 4; ++i){
        int q = qt*8 + half*4 + i;
        float4 wr = *(const float4*)(Wih + q*128       + k4*4);
        float4 wz = *(const float4*)(Wih + (64+q)*128  + k4*4);
        float4 wn = *(const float4*)(Wih + (128+q)*128 + k4*4);
        aR[i] = fmaf(wr.x,x0,fmaf(wr.y,x1,fmaf(wr.z,x2,fmaf(wr.w,x3,aR[i]))));
        aZ[i] = fmaf(wz.x,x0,fmaf(wz.y,x1,fmaf(wz.z,x2,fmaf(wz.w,x3,aZ[i]))));
        aN[i] = fmaf(wn.x,x0,fmaf(wn.y,x1,fmaf(wn.z,x2,fmaf(wn.w,x3,aN[i]))));
      }
    }
    // W_ih x agg, k = 64..127 (rows 128..191)
    #pragma unroll 2
    for(int k4 = 0; k4 < 16; ++k4){
      float x0 = xT[128+k4*4+0][lane];
      float x1 = xT[128+k4*4+1][lane];
      float x2 = xT[128+k4*4+2][lane];
      float x3 = xT[128+k4*4+3][lane];
      #pragma unroll
      for(int i = 0; i < 4; ++i){
        int q = qt*8 + half*4 + i;
        float4 wr = *(const float4*)(Wih + q*128       + 64 + k4*4);
        float4 wz = *(const float4*)(Wih + (64+q)*128  + 64 + k4*4);
        float4 wn = *(const float4*)(Wih + (128+q)*128 + 64 + k4*4);
        aR[i] = fmaf(wr.x,x0,fmaf(wr.y,x1,fmaf(wr.z,x2,fmaf(wr.w,x3,aR[i]))));
        aZ[i] = fmaf(wz.x,x0,fmaf(wz.y,x1,fmaf(wz.z,x2,fmaf(wz.w,x3,aZ[i]))));
        aN[i] = fmaf(wn.x,x0,fmaf(wn.y,x1,fmaf(wn.z,x2,fmaf(wn.w,x3,aN[i]))));
      }
    }
    // W_hh x h, k = 0..63 (rows 64..127)
    #pragma unroll 2
    for(int k4 = 0; k4 < 16; ++k4){
      float x0 = xT[64+k4*4+0][lane];
      float x1 = xT[64+k4*4+1][lane];
      float x2 = xT[64+k4*4+2][lane];
      float x3 = xT[64+k4*4+3][lane];
      #pragma unroll
      for(int i = 0; i < 4; ++i){
        int q = qt*8 + half*4 + i;
        float4 wr = *(const float4*)(Whh + q*64       + k4*4);
        float4 wz = *(const float4*)(Whh + (64+q)*64  + k4*4);
        float4 wh = *(const float4*)(Whh + (128+q)*64 + k4*4);
        aR[i] = fmaf(wr.x,x0,fmaf(wr.y,x1,fmaf(wr.z,x2,fmaf(wr.w,x3,aR[i]))));
        aZ[i] = fmaf(wz.x,x0,fmaf(wz.y,x1,fmaf(wz.z,x2,fmaf(wz.w,x3,aZ[i]))));
        aH[i] = fmaf(wh.x,x0,fmaf(wh.y,x1,fmaf(wh.z,x2,fmaf(wh.w,x3,aH[i]))));
      }
    }
    #pragma unroll
    for(int i = 0; i < 4; ++i){
      int q = qt*8 + half*4 + i;
      float r = sigf(aR[i]);
      float z = sigf(aZ[i]);
      float nn = tanhfast(aN[i] + r*aH[i]);
      float hq = xT[64+q][lane];
      hout[half*4 + i] = (1.f - z)*nn + z*hq;
    }
  }
  __syncthreads();   // all waves done reading agg rows 0..63 -> reuse as ht
  #pragma unroll
  for(int i = 0; i < 8; ++i){
    int q = qt*8 + i;
    xT[q][lane] = hout[i];
  }
  __syncthreads();
  for(int ii = 0; ii < 8; ++ii){
    int i = wv*8 + ii;
    int n = base + i;
    if(n < N) hnext[n*D64 + lane] = xT[lane][i];
  }
}

// ---------------- gated readout: register-accumulated partials, no atomics ----------------
__global__ __launch_bounds__(512) void k5_read(
    const float* __restrict__ h, const float* __restrict__ Wfm,
    const float* __restrict__ bfm, const float* __restrict__ Wgm,
    const float* __restrict__ bgm, float* __restrict__ partials, int N, int nT){
  __shared__ float xT[64][67];
  const int lane = threadIdx.x & 63;
  const int wv   = __builtin_amdgcn_readfirstlane(threadIdx.x >> 6);
  float acc[2][8];
  #pragma unroll
  for(int t = 0; t < 2; ++t)
    #pragma unroll
    for(int jj = 0; jj < 8; ++jj) acc[t][jj] = 0.f;

  for(int tile = blockIdx.x; tile < nT; tile += NB5){
    const int base = tile * 64;
    __syncthreads();
    for(int ii = 0; ii < 8; ++ii){
      int i = wv*8 + ii;
      int n = base + i; if(n >= N) n = N - 1;
      xT[lane][i] = h[n*D64 + lane];
    }
    __syncthreads();
    const bool valid = (base + lane) < N;
    for(int t = 0; t < 2; ++t){
      const int jt = wv + t*8;
      float aF[8], aG[8];
      #pragma unroll
      for(int jj = 0; jj < 8; ++jj){
        int j = jt*8 + jj;
        aF[jj] = bfm[j]; aG[jj] = bgm[j];
      }
      #pragma unroll 2
      for(int k4 = 0; k4 < 16; ++k4){
        float x0 = xT[k4*4+0][lane];
        float x1 = xT[k4*4+1][lane];
        float x2 = xT[k4*4+2][lane];
        float x3 = xT[k4*4+3][lane];
        #pragma unroll
        for(int jj = 0; jj < 8; ++jj){
          int j = jt*8 + jj;
          float4 wf = *(const float4*)(Wfm + j*64 + k4*4);
          float4 wg = *(const float4*)(Wgm + j*64 + k4*4);
          aF[jj] = fmaf(wf.x,x0,fmaf(wf.y,x1,fmaf(wf.z,x2,fmaf(wf.w,x3,aF[jj]))));
          aG[jj] = fmaf(wg.x,x0,fmaf(wg.y,x1,fmaf(wg.z,x2,fmaf(wg.w,x3,aG[jj]))));
        }
      }
      if(valid){
        #pragma unroll
        for(int jj = 0; jj < 8; ++jj)
          acc[t][jj] += aF[jj] * sigf(aG[jj]);
      }
    }
  }
  #pragma unroll
  for(int t = 0; t < 2; ++t)
    for(int jj = 0; jj < 8; ++jj){
      float val = acc[t][jj];
      #pragma unroll
      for(int o = 32; o > 0; o >>= 1) val += __shfl_xor(val, o, 64);
      if(lane == 0) partials[blockIdx.x*128 + (wv + t*8)*8 + jj] = val;
    }
}

__global__ void k6_dec(const float* __restrict__ partials, int nb,
                       const float* __restrict__ h,
                       const float* __restrict__ Wdec, const float* __restrict__ bdec,
                       const int* __restrict__ tgt, float* __restrict__ out){
  __shared__ float sm[256];
  int t = threadIdx.x;
  float v = 0.f;
  if(t < 128){
    float s0 = 0.f, s1 = 0.f, s2 = 0.f, s3 = 0.f;
    for(int b = 0; b + 4 <= nb; b += 4){
      s0 += partials[(b+0)*128 + t];
      s1 += partials[(b+1)*128 + t];
      s2 += partials[(b+2)*128 + t];
      s3 += partials[(b+3)*128 + t];
    }
    v = ((s0 + s1) + (s2 + s3)) * Wdec[t];
  } else if(t < 192){
    v = h[tgt[0]*D64 + (t - 128)] * Wdec[t];
  }
  sm[t] = v;
  __syncthreads();
  for(int s = 128; s > 0; s >>= 1){
    if(t < s) sm[t] += sm[t + s];
    __syncthreads();
  }
  if(t == 0) out[0] = sm[0] + bdec[0];
}

extern "C" void kernel_launch(void* const* d_in, const int* in_sizes, int n_in,
                              void* d_out, int out_size, void* d_ws, size_t ws_size,
                              hipStream_t stream){
  const float* nodev = (const float*)d_in[0];
  const float* ev    = (const float*)d_in[1];
  const float* Wef   = (const float*)d_in[2];
  const float* bef   = (const float*)d_in[3];
  const float* Wer   = (const float*)d_in[4];
  const float* ber   = (const float*)d_in[5];
  const float* Wih   = (const float*)d_in[6];
  const float* Whh   = (const float*)d_in[7];
  const float* bih   = (const float*)d_in[8];
  const float* bhh   = (const float*)d_in[9];
  const float* Wfm   = (const float*)d_in[10];
  const float* bfm   = (const float*)d_in[11];
  const float* Wgm   = (const float*)d_in[12];
  const float* bgm   = (const float*)d_in[13];
  const float* Wdec  = (const float*)d_in[14];
  const float* bdec  = (const float*)d_in[15];
  const int* uidx    = (const int*)d_in[16];
  const int* vidx    = (const int*)d_in[17];
  const int* tgt     = (const int*)d_in[18];

  const int N = in_sizes[0] / 64;
  const int E = in_sizes[16];
  const int R = in_sizes[2] / (128*144);

  char* w = (char*)d_ws;
  auto alloc = [&](size_t bytes) -> void* {
    void* p = (void*)w;
    w += (bytes + 255) & ~(size_t)255;
    return p;
  };
  int* off       = (int*)alloc(((size_t)2*N + 1) * 4);
  int* cur       = (int*)alloc((size_t)2*N * 4);
  int* rows      = (int*)alloc((size_t)2*E * 4);
  int* part      = (int*)alloc(4096 * 4);
  float* Ein     = (float*)alloc((size_t)N*16*4);
  float* Eout    = (float*)alloc((size_t)N*16*4);
  float* Sin     = (float*)alloc((size_t)N*64*4);
  float* Sout    = (float*)alloc((size_t)N*64*4);
  float* hA      = (float*)alloc((size_t)N*64*4);
  float* hB      = (float*)alloc((size_t)N*64*4);
  float* partial = (float*)alloc((size_t)NB5*128*4);

  hipMemsetAsync(off, 0, ((size_t)2*N+1)*4, stream);

  int eb = (E + 255)/256;
  k_count<<<eb, 256, 0, stream>>>(uidx, vidx, off, N, E);
  int M = 2*N;
  int nb = (M + 255)/256;
  k_scan1<<<nb, 256, 0, stream>>>(off, part, M);
  k_scan2<<<1, 1024, 0, stream>>>(part, nb);
  k_scan3<<<nb, 256, 0, stream>>>(off, part, cur, M, 2*E);
  k_fill<<<eb, 256, 0, stream>>>(uidx, vidx, cur, rows, N, E);
  int wb = (N + 3)/4;
  k_einout<<<wb, 256, 0, stream>>>(ev, off, rows, Ein, Eout, N);

  int nT = (N + 63)/64;
  const float* hcur = nodev;
  float* bufs[2] = {hA, hB};
  for(int r = 0; r < R; ++r){
    k_aggr<<<wb, 256, 0, stream>>>(hcur, off, rows, uidx, vidx, Sin, Sout, N);
    float* hn = bufs[r & 1];
    k34_fused<<<nT, 512, 0, stream>>>(hcur, Sin, Sout, Ein, Eout, off,
                                      Wef + (size_t)r*128*144, bef + r*128,
                                      Wer + (size_t)r*128*144, ber + r*128,
                                      Wih + (size_t)r*192*128, Whh + (size_t)r*192*64,
                                      bih + r*192, bhh + r*192, hn, N);
    hcur = hn;
  }
  k5_read<<<NB5, 512, 0, stream>>>(hcur, Wfm, bfm, Wgm, bgm, partial, N, nT);
  k6_dec<<<1, 256, 0, stream>>>(partial, NB5, hcur, Wdec, bdec, tgt, (float*)d_out);
}

// Round 7
// 1133.017 us; speedup vs baseline: 3.0498x; 1.2292x over previous
//
#include <hip/hip_runtime.h>
#include <math.h>

#define D64 64
#define ES16 16
#define NB5 256

__device__ __forceinline__ float sigf(float x){ return 1.0f/(1.0f + __expf(-x)); }
__device__ __forceinline__ float tanhfast(float x){ return 2.0f*sigf(2.0f*x) - 1.0f; }

// ---------------- CSR build ----------------
__global__ void k_count(const int* __restrict__ u, const int* __restrict__ v,
                        int* __restrict__ cnt, int N, int E){
  int e = blockIdx.x*256 + threadIdx.x;
  if(e < E){
    atomicAdd(&cnt[v[e]], 1);
    atomicAdd(&cnt[N + u[e]], 1);
  }
}

__global__ void k_scan1(const int* __restrict__ cnt, int* __restrict__ part, int M){
  __shared__ int sm[256];
  int i = blockIdx.x*256 + threadIdx.x;
  sm[threadIdx.x] = (i < M) ? cnt[i] : 0;
  __syncthreads();
  for(int s = 128; s > 0; s >>= 1){
    if(threadIdx.x < s) sm[threadIdx.x] += sm[threadIdx.x + s];
    __syncthreads();
  }
  if(threadIdx.x == 0) part[blockIdx.x] = sm[0];
}

__global__ void k_scan2(int* __restrict__ part, int nb){
  __shared__ int sm[1024];
  int t = threadIdx.x;
  int orig = (t < nb) ? part[t] : 0;
  sm[t] = orig;
  __syncthreads();
  for(int off = 1; off < 1024; off <<= 1){
    int add = (t >= off) ? sm[t - off] : 0;
    __syncthreads();
    sm[t] += add;
    __syncthreads();
  }
  if(t < nb) part[t] = sm[t] - orig;  // exclusive prefix
}

__global__ void k_scan3(int* __restrict__ cnt, const int* __restrict__ part,
                        int* __restrict__ cur, int M, int total){
  __shared__ int sm[256];
  int t = threadIdx.x;
  int i = blockIdx.x*256 + t;
  int orig = (i < M) ? cnt[i] : 0;
  sm[t] = orig;
  __syncthreads();
  for(int off = 1; off < 256; off <<= 1){
    int add = (t >= off) ? sm[t - off] : 0;
    __syncthreads();
    sm[t] += add;
    __syncthreads();
  }
  if(i < M){
    int excl = part[blockIdx.x] + sm[t] - orig;
    cnt[i] = excl;
    cur[i] = excl;
  }
  if(i == 0) cnt[M] = total;
}

// rows[p] = edge id (for k_einout); srcs[p] = opposite endpoint (for k_aggr:
// removes one dependent-load level from the gather chain).
__global__ void k_fill(const int* __restrict__ u, const int* __restrict__ v,
                       int* __restrict__ cur, int* __restrict__ rows,
                       int* __restrict__ srcs, int N, int E){
  int e = blockIdx.x*256 + threadIdx.x;
  if(e < E){
    int uu = u[e], vv = v[e];
    int p = atomicAdd(&cur[vv], 1);     rows[p] = e; srcs[p] = uu;
    int q = atomicAdd(&cur[N + uu], 1); rows[q] = e; srcs[q] = vv;
  }
}

// ---------------- round-constant edge-feature sums ----------------
__global__ void k_einout(const float* __restrict__ ev, const int* __restrict__ off,
                         const int* __restrict__ rows,
                         float* __restrict__ Ein, float* __restrict__ Eout, int N){
  int n = (blockIdx.x*blockDim.x + threadIdx.x) >> 6;
  int lane = threadIdx.x & 63;
  if(n >= N) return;
  int t = lane & 15, s = lane >> 4;
  float a = 0.f;
  int p1 = off[n+1];
  for(int p = off[n] + s; p < p1; p += 4) a += ev[rows[p]*ES16 + t];
  a += __shfl_xor(a, 16, 64);
  a += __shfl_xor(a, 32, 64);
  if(lane < 16) Ein[n*ES16 + lane] = a;
  float b = 0.f;
  p1 = off[N+n+1];
  for(int p = off[N+n] + s; p < p1; p += 4) b += ev[rows[p]*ES16 + t];
  b += __shfl_xor(b, 16, 64);
  b += __shfl_xor(b, 32, 64);
  if(lane < 16) Eout[n*ES16 + lane] = b;
}

// ---------------- per-round sparse aggregation ----------------
// One wave per (node, direction): gw in [0, 2N). Direct src gather (no edge
// indirection), 4 independent loads in flight.
__global__ void k_aggr(const float* __restrict__ h, const int* __restrict__ off,
                       const int* __restrict__ srcs,
                       float* __restrict__ Sin, float* __restrict__ Sout, int N){
  int gw = (blockIdx.x*blockDim.x + threadIdx.x) >> 6;
  int lane = threadIdx.x & 63;
  if(gw >= 2*N) return;
  int p = off[gw], p1 = off[gw+1];
  float sA = 0.f, sB = 0.f;
  for(; p + 4 <= p1; p += 4){
    int s0 = srcs[p], s1 = srcs[p+1], s2 = srcs[p+2], s3 = srcs[p+3];
    float a = h[(size_t)s0*D64 + lane];
    float b = h[(size_t)s1*D64 + lane];
    float c = h[(size_t)s2*D64 + lane];
    float d = h[(size_t)s3*D64 + lane];
    sA += a + b; sB += c + d;
  }
  for(; p < p1; ++p) sA += h[(size_t)srcs[p]*D64 + lane];
  float s = sA + sB;
  if(gw < N) Sin[(size_t)gw*D64 + lane] = s;
  else       Sout[(size_t)(gw-N)*D64 + lane] = s;
}

// ---------------- fused node transform + GRU ----------------
// 512 threads = 8 waves per 64-node tile.
// Phase A: wave wv computes agg cols jbase..jbase+15 (jbase = wv*16) for all
// 64 nodes in ONE pass (was 8 cols x 2 passes): each LDS x-quad feeds 2x the
// FMAs -> phase-A ds_reads ~384->256/wave, weight s_load stream halves.
// Inner jj kept in 8-wide sub-blocks to bound live weight SGPRs (<=64 words).
// agg then staged into dead Sin/Sout LDS rows; Phase B GRU (8 q/wave, single
// pass over k) runs in-place. wv uniform via readfirstlane -> s_load weights.
// NOTE: plain __launch_bounds__(512) — a (512,6) clamp forced VGPR=40 and ~1 GB
// of scratch spill per dispatch (round-3 counters). Do not re-add.
__global__ __launch_bounds__(512) void k34_fused(
    const float* __restrict__ h, const float* __restrict__ Sin,
    const float* __restrict__ Sout, const float* __restrict__ Ein,
    const float* __restrict__ Eout, const int* __restrict__ off,
    const float* __restrict__ Wef, const float* __restrict__ bef,
    const float* __restrict__ Wer, const float* __restrict__ ber,
    const float* __restrict__ Wih, const float* __restrict__ Whh,
    const float* __restrict__ bih, const float* __restrict__ bhh,
    float* __restrict__ hnext, int N){
  __shared__ float xT[192][67];
  const int lane = threadIdx.x & 63;
  const int wv   = __builtin_amdgcn_readfirstlane(threadIdx.x >> 6);
  const int base = blockIdx.x * 64;
  for(int ii = 0; ii < 8; ++ii){
    int i = wv*8 + ii;
    int n = base + i; if(n >= N) n = N - 1;
    xT[lane][i]       = Sin[n*D64 + lane];
    xT[64+lane][i]    = h[n*D64 + lane];
    xT[128+lane][i]   = Sout[n*D64 + lane];
  }
  __syncthreads();
  int node = base + lane; if(node >= N) node = N - 1;
  const float fi = (float)(off[node+1] - off[node]);
  const float fo = (float)(off[N+node+1] - off[N+node]);
  float4 xi0 = *(const float4*)(Ein  + node*ES16 + 0);
  float4 xi1 = *(const float4*)(Ein  + node*ES16 + 4);
  float4 xi2 = *(const float4*)(Ein  + node*ES16 + 8);
  float4 xi3 = *(const float4*)(Ein  + node*ES16 + 12);
  float4 xo0 = *(const float4*)(Eout + node*ES16 + 0);
  float4 xo1 = *(const float4*)(Eout + node*ES16 + 4);
  float4 xo2 = *(const float4*)(Eout + node*ES16 + 8);
  float4 xo3 = *(const float4*)(Eout + node*ES16 + 12);
  const bool valid = (base + lane) < N;

  const int jbase = wv*16;
  float acc[16];
  #pragma unroll
  for(int jj = 0; jj < 16; ++jj){
    int j = jbase + jj;
    acc[jj] = fi*bef[j] + fo*ber[j];
  }
  // Sin block: Wef cols 0..63
  for(int k4 = 0; k4 < 16; ++k4){
    float x0 = xT[k4*4+0][lane];
    float x1 = xT[k4*4+1][lane];
    float x2 = xT[k4*4+2][lane];
    float x3 = xT[k4*4+3][lane];
    #pragma unroll
    for(int jj = 0; jj < 16; ++jj){
      float4 w = *(const float4*)(Wef + (jbase+jj)*144 + k4*4);
      acc[jj] = fmaf(w.x,x0,fmaf(w.y,x1,fmaf(w.z,x2,fmaf(w.w,x3,acc[jj]))));
    }
  }
  // h block: Wef cols 64..127 (xfi) and Wer cols 0..63 (xfo) share LDS reads.
  // jj split 8+8 to bound live weight SGPRs.
  for(int k4 = 0; k4 < 16; ++k4){
    float h0 = xT[64+k4*4+0][lane];
    float h1 = xT[64+k4*4+1][lane];
    float h2 = xT[64+k4*4+2][lane];
    float h3 = xT[64+k4*4+3][lane];
    float f0 = fi*h0, f1 = fi*h1, f2 = fi*h2, f3 = fi*h3;
    float r0 = fo*h0, r1 = fo*h1, r2 = fo*h2, r3 = fo*h3;
    for(int jh = 0; jh < 2; ++jh){
      #pragma unroll
      for(int jx = 0; jx < 8; ++jx){
        int jj = jh*8 + jx;
        int j = jbase + jj;
        float4 wf = *(const float4*)(Wef + j*144 + 64 + k4*4);
        float4 wr = *(const float4*)(Wer + j*144 + k4*4);
        acc[jj] = fmaf(wf.x,f0,fmaf(wf.y,f1,fmaf(wf.z,f2,fmaf(wf.w,f3,acc[jj]))));
        acc[jj] = fmaf(wr.x,r0,fmaf(wr.y,r1,fmaf(wr.z,r2,fmaf(wr.w,r3,acc[jj]))));
      }
    }
  }
  // E blocks (register-resident x, scalar weights)
  for(int jh = 0; jh < 2; ++jh){
    #pragma unroll
    for(int jx = 0; jx < 8; ++jx){
      int jj = jh*8 + jx;
      int j = jbase + jj;
      const float4* wfp = (const float4*)(Wef + j*144 + 128);
      const float4* wrp = (const float4*)(Wer + j*144 + 128);
      float4 wf, wr;
      wf = wfp[0]; wr = wrp[0];
      acc[jj] = fmaf(wf.x,xi0.x,fmaf(wf.y,xi0.y,fmaf(wf.z,xi0.z,fmaf(wf.w,xi0.w,acc[jj]))));
      acc[jj] = fmaf(wr.x,xo0.x,fmaf(wr.y,xo0.y,fmaf(wr.z,xo0.z,fmaf(wr.w,xo0.w,acc[jj]))));
      wf = wfp[1]; wr = wrp[1];
      acc[jj] = fmaf(wf.x,xi1.x,fmaf(wf.y,xi1.y,fmaf(wf.z,xi1.z,fmaf(wf.w,xi1.w,acc[jj]))));
      acc[jj] = fmaf(wr.x,xo1.x,fmaf(wr.y,xo1.y,fmaf(wr.z,xo1.z,fmaf(wr.w,xo1.w,acc[jj]))));
      wf = wfp[2]; wr = wrp[2];
      acc[jj] = fmaf(wf.x,xi2.x,fmaf(wf.y,xi2.y,fmaf(wf.z,xi2.z,fmaf(wf.w,xi2.w,acc[jj]))));
      acc[jj] = fmaf(wr.x,xo2.x,fmaf(wr.y,xo2.y,fmaf(wr.z,xo2.z,fmaf(wr.w,xo2.w,acc[jj]))));
      wf = wfp[3]; wr = wrp[3];
      acc[jj] = fmaf(wf.x,xi3.x,fmaf(wf.y,xi3.y,fmaf(wf.z,xi3.z,fmaf(wf.w,xi3.w,acc[jj]))));
      acc[jj] = fmaf(wr.x,xo3.x,fmaf(wr.y,xo3.y,fmaf(wr.z,xo3.z,fmaf(wr.w,xo3.w,acc[jj]))));
    }
  }
  // Sout block: Wer cols 64..127
  for(int k4 = 0; k4 < 16; ++k4){
    float x0 = xT[128+k4*4+0][lane];
    float x1 = xT[128+k4*4+1][lane];
    float x2 = xT[128+k4*4+2][lane];
    float x3 = xT[128+k4*4+3][lane];
    #pragma unroll
    for(int jj = 0; jj < 16; ++jj){
      float4 w = *(const float4*)(Wer + (jbase+jj)*144 + 64 + k4*4);
      acc[jj] = fmaf(w.x,x0,fmaf(w.y,x1,fmaf(w.z,x2,fmaf(w.w,x3,acc[jj]))));
    }
  }

  // ---- agg -> LDS (reuse Sin/Sout rows); h rows 64..127 stay live ----
  __syncthreads();   // all waves done READING Sin/Sout rows
  #pragma unroll
  for(int jj = 0; jj < 16; ++jj){
    int c = jbase + jj;                       // wave-uniform side: wv<4 -> c<64
    int row = (c < 64) ? c : (128 + c - 64);
    xT[row][lane] = acc[jj];
  }
  __syncthreads();

  // ---- Phase B: GRU, single pass over k, 8 q-outputs per wave ----
  const int qt = wv;
  float aR[8], aZ[8], aN[8], aH[8];
  #pragma unroll
  for(int i = 0; i < 8; ++i){
    int q = qt*8 + i;
    aR[i] = bih[q]      + bhh[q];
    aZ[i] = bih[64+q]   + bhh[64+q];
    aN[i] = bih[128+q];
    aH[i] = bhh[128+q];
  }
  // W_ih x agg, k = 0..63 (rows 0..63)
  for(int k4 = 0; k4 < 16; ++k4){
    float x0 = xT[k4*4+0][lane];
    float x1 = xT[k4*4+1][lane];
    float x2 = xT[k4*4+2][lane];
    float x3 = xT[k4*4+3][lane];
    for(int ih = 0; ih < 2; ++ih){
      #pragma unroll
      for(int ix = 0; ix < 4; ++ix){
        int i = ih*4 + ix;
        int q = qt*8 + i;
        float4 wr = *(const float4*)(Wih + q*128       + k4*4);
        float4 wz = *(const float4*)(Wih + (64+q)*128  + k4*4);
        float4 wn = *(const float4*)(Wih + (128+q)*128 + k4*4);
        aR[i] = fmaf(wr.x,x0,fmaf(wr.y,x1,fmaf(wr.z,x2,fmaf(wr.w,x3,aR[i]))));
        aZ[i] = fmaf(wz.x,x0,fmaf(wz.y,x1,fmaf(wz.z,x2,fmaf(wz.w,x3,aZ[i]))));
        aN[i] = fmaf(wn.x,x0,fmaf(wn.y,x1,fmaf(wn.z,x2,fmaf(wn.w,x3,aN[i]))));
      }
    }
  }
  // W_ih x agg, k = 64..127 (rows 128..191)
  for(int k4 = 0; k4 < 16; ++k4){
    float x0 = xT[128+k4*4+0][lane];
    float x1 = xT[128+k4*4+1][lane];
    float x2 = xT[128+k4*4+2][lane];
    float x3 = xT[128+k4*4+3][lane];
    for(int ih = 0; ih < 2; ++ih){
      #pragma unroll
      for(int ix = 0; ix < 4; ++ix){
        int i = ih*4 + ix;
        int q = qt*8 + i;
        float4 wr = *(const float4*)(Wih + q*128       + 64 + k4*4);
        float4 wz = *(const float4*)(Wih + (64+q)*128  + 64 + k4*4);
        float4 wn = *(const float4*)(Wih + (128+q)*128 + 64 + k4*4);
        aR[i] = fmaf(wr.x,x0,fmaf(wr.y,x1,fmaf(wr.z,x2,fmaf(wr.w,x3,aR[i]))));
        aZ[i] = fmaf(wz.x,x0,fmaf(wz.y,x1,fmaf(wz.z,x2,fmaf(wz.w,x3,aZ[i]))));
        aN[i] = fmaf(wn.x,x0,fmaf(wn.y,x1,fmaf(wn.z,x2,fmaf(wn.w,x3,aN[i]))));
      }
    }
  }
  // W_hh x h, k = 0..63 (rows 64..127)
  for(int k4 = 0; k4 < 16; ++k4){
    float x0 = xT[64+k4*4+0][lane];
    float x1 = xT[64+k4*4+1][lane];
    float x2 = xT[64+k4*4+2][lane];
    float x3 = xT[64+k4*4+3][lane];
    for(int ih = 0; ih < 2; ++ih){
      #pragma unroll
      for(int ix = 0; ix < 4; ++ix){
        int i = ih*4 + ix;
        int q = qt*8 + i;
        float4 wr = *(const float4*)(Whh + q*64       + k4*4);
        float4 wz = *(const float4*)(Whh + (64+q)*64  + k4*4);
        float4 wh = *(const float4*)(Whh + (128+q)*64 + k4*4);
        aR[i] = fmaf(wr.x,x0,fmaf(wr.y,x1,fmaf(wr.z,x2,fmaf(wr.w,x3,aR[i]))));
        aZ[i] = fmaf(wz.x,x0,fmaf(wz.y,x1,fmaf(wz.z,x2,fmaf(wz.w,x3,aZ[i]))));
        aH[i] = fmaf(wh.x,x0,fmaf(wh.y,x1,fmaf(wh.z,x2,fmaf(wh.w,x3,aH[i]))));
      }
    }
  }
  float hout[8];
  #pragma unroll
  for(int i = 0; i < 8; ++i){
    int q = qt*8 + i;
    float r = sigf(aR[i]);
    float z = sigf(aZ[i]);
    float nn = tanhfast(aN[i] + r*aH[i]);
    float hq = xT[64+q][lane];
    hout[i] = (1.f - z)*nn + z*hq;
  }
  __syncthreads();   // all waves done reading agg rows 0..63 -> reuse as ht
  #pragma unroll
  for(int i = 0; i < 8; ++i){
    int q = qt*8 + i;
    xT[q][lane] = hout[i];
  }
  __syncthreads();
  for(int ii = 0; ii < 8; ++ii){
    int i = wv*8 + ii;
    int n = base + i;
    if(n < N) hnext[n*D64 + lane] = xT[lane][i];
  }
}

// ---------------- gated readout: register-accumulated partials, no atomics ----------------
__global__ __launch_bounds__(512) void k5_read(
    const float* __restrict__ h, const float* __restrict__ Wfm,
    const float* __restrict__ bfm, const float* __restrict__ Wgm,
    const float* __restrict__ bgm, float* __restrict__ partials, int N, int nT){
  __shared__ float xT[64][67];
  const int lane = threadIdx.x & 63;
  const int wv   = __builtin_amdgcn_readfirstlane(threadIdx.x >> 6);
  float acc[2][8];
  #pragma unroll
  for(int t = 0; t < 2; ++t)
    #pragma unroll
    for(int jj = 0; jj < 8; ++jj) acc[t][jj] = 0.f;

  for(int tile = blockIdx.x; tile < nT; tile += NB5){
    const int base = tile * 64;
    __syncthreads();
    for(int ii = 0; ii < 8; ++ii){
      int i = wv*8 + ii;
      int n = base + i; if(n >= N) n = N - 1;
      xT[lane][i] = h[n*D64 + lane];
    }
    __syncthreads();
    const bool valid = (base + lane) < N;
    for(int t = 0; t < 2; ++t){
      const int jt = wv + t*8;
      float aF[8], aG[8];
      #pragma unroll
      for(int jj = 0; jj < 8; ++jj){
        int j = jt*8 + jj;
        aF[jj] = bfm[j]; aG[jj] = bgm[j];
      }
      #pragma unroll 2
      for(int k4 = 0; k4 < 16; ++k4){
        float x0 = xT[k4*4+0][lane];
        float x1 = xT[k4*4+1][lane];
        float x2 = xT[k4*4+2][lane];
        float x3 = xT[k4*4+3][lane];
        #pragma unroll
        for(int jj = 0; jj < 8; ++jj){
          int j = jt*8 + jj;
          float4 wf = *(const float4*)(Wfm + j*64 + k4*4);
          float4 wg = *(const float4*)(Wgm + j*64 + k4*4);
          aF[jj] = fmaf(wf.x,x0,fmaf(wf.y,x1,fmaf(wf.z,x2,fmaf(wf.w,x3,aF[jj]))));
          aG[jj] = fmaf(wg.x,x0,fmaf(wg.y,x1,fmaf(wg.z,x2,fmaf(wg.w,x3,aG[jj]))));
        }
      }
      if(valid){
        #pragma unroll
        for(int jj = 0; jj < 8; ++jj)
          acc[t][jj] += aF[jj] * sigf(aG[jj]);
      }
    }
  }
  #pragma unroll
  for(int t = 0; t < 2; ++t)
    for(int jj = 0; jj < 8; ++jj){
      float val = acc[t][jj];
      #pragma unroll
      for(int o = 32; o > 0; o >>= 1) val += __shfl_xor(val, o, 64);
      if(lane == 0) partials[blockIdx.x*128 + (wv + t*8)*8 + jj] = val;
    }
}

__global__ void k6_dec(const float* __restrict__ partials, int nb,
                       const float* __restrict__ h,
                       const float* __restrict__ Wdec, const float* __restrict__ bdec,
                       const int* __restrict__ tgt, float* __restrict__ out){
  __shared__ float sm[256];
  int t = threadIdx.x;
  float v = 0.f;
  if(t < 128){
    float s0 = 0.f, s1 = 0.f, s2 = 0.f, s3 = 0.f;
    for(int b = 0; b + 4 <= nb; b += 4){
      s0 += partials[(b+0)*128 + t];
      s1 += partials[(b+1)*128 + t];
      s2 += partials[(b+2)*128 + t];
      s3 += partials[(b+3)*128 + t];
    }
    v = ((s0 + s1) + (s2 + s3)) * Wdec[t];
  } else if(t < 192){
    v = h[tgt[0]*D64 + (t - 128)] * Wdec[t];
  }
  sm[t] = v;
  __syncthreads();
  for(int s = 128; s > 0; s >>= 1){
    if(t < s) sm[t] += sm[t + s];
    __syncthreads();
  }
  if(t == 0) out[0] = sm[0] + bdec[0];
}

extern "C" void kernel_launch(void* const* d_in, const int* in_sizes, int n_in,
                              void* d_out, int out_size, void* d_ws, size_t ws_size,
                              hipStream_t stream){
  const float* nodev = (const float*)d_in[0];
  const float* ev    = (const float*)d_in[1];
  const float* Wef   = (const float*)d_in[2];
  const float* bef   = (const float*)d_in[3];
  const float* Wer   = (const float*)d_in[4];
  const float* ber   = (const float*)d_in[5];
  const float* Wih   = (const float*)d_in[6];
  const float* Whh   = (const float*)d_in[7];
  const float* bih   = (const float*)d_in[8];
  const float* bhh   = (const float*)d_in[9];
  const float* Wfm   = (const float*)d_in[10];
  const float* bfm   = (const float*)d_in[11];
  const float* Wgm   = (const float*)d_in[12];
  const float* bgm   = (const float*)d_in[13];
  const float* Wdec  = (const float*)d_in[14];
  const float* bdec  = (const float*)d_in[15];
  const int* uidx    = (const int*)d_in[16];
  const int* vidx    = (const int*)d_in[17];
  const int* tgt     = (const int*)d_in[18];

  const int N = in_sizes[0] / 64;
  const int E = in_sizes[16];
  const int R = in_sizes[2] / (128*144);

  char* w = (char*)d_ws;
  auto alloc = [&](size_t bytes) -> void* {
    void* p = (void*)w;
    w += (bytes + 255) & ~(size_t)255;
    return p;
  };
  int* off       = (int*)alloc(((size_t)2*N + 1) * 4);
  int* cur       = (int*)alloc((size_t)2*N * 4);
  int* rows      = (int*)alloc((size_t)2*E * 4);
  int* srcs      = (int*)alloc((size_t)2*E * 4);
  int* part      = (int*)alloc(4096 * 4);
  float* Ein     = (float*)alloc((size_t)N*16*4);
  float* Eout    = (float*)alloc((size_t)N*16*4);
  float* Sin     = (float*)alloc((size_t)N*64*4);
  float* Sout    = (float*)alloc((size_t)N*64*4);
  float* hA      = (float*)alloc((size_t)N*64*4);
  float* hB      = (float*)alloc((size_t)N*64*4);
  float* partial = (float*)alloc((size_t)NB5*128*4);

  hipMemsetAsync(off, 0, ((size_t)2*N+1)*4, stream);

  int eb = (E + 255)/256;
  k_count<<<eb, 256, 0, stream>>>(uidx, vidx, off, N, E);
  int M = 2*N;
  int nb = (M + 255)/256;
  k_scan1<<<nb, 256, 0, stream>>>(off, part, M);
  k_scan2<<<1, 1024, 0, stream>>>(part, nb);
  k_scan3<<<nb, 256, 0, stream>>>(off, part, cur, M, 2*E);
  k_fill<<<eb, 256, 0, stream>>>(uidx, vidx, cur, rows, srcs, N, E);
  int wb = (N + 3)/4;
  k_einout<<<wb, 256, 0, stream>>>(ev, off, rows, Ein, Eout, N);

  int nT = (N + 63)/64;
  int ab = (2*N + 3)/4;
  const float* hcur = nodev;
  float* bufs[2] = {hA, hB};
  for(int r = 0; r < R; ++r){
    k_aggr<<<ab, 256, 0, stream>>>(hcur, off, srcs, Sin, Sout, N);
    float* hn = bufs[r & 1];
    k34_fused<<<nT, 512, 0, stream>>>(hcur, Sin, Sout, Ein, Eout, off,
                                      Wef + (size_t)r*128*144, bef + r*128,
                                      Wer + (size_t)r*128*144, ber + r*128,
                                      Wih + (size_t)r*192*128, Whh + (size_t)r*192*64,
                                      bih + r*192, bhh + r*192, hn, N);
    hcur = hn;
  }
  k5_read<<<NB5, 512, 0, stream>>>(hcur, Wfm, bfm, Wgm, bgm, partial, N, nT);
  k6_dec<<<1, 256, 0, stream>>>(partial, NB5, hcur, Wdec, bdec, tgt, (float*)d_out);
}

// Round 8
// 1129.506 us; speedup vs baseline: 3.0593x; 1.0031x over previous
//
#include <hip/hip_runtime.h>
#include <math.h>

#define D64 64
#define ES16 16
#define NB5 256
#define XSTR 196   // LDS row stride in floats: 49 float4-groups (odd) -> b128 conflict-free

__device__ __forceinline__ float sigf(float x){ return 1.0f/(1.0f + __expf(-x)); }
__device__ __forceinline__ float tanhfast(float x){ return 2.0f*sigf(2.0f*x) - 1.0f; }

// ---------------- CSR build ----------------
__global__ void k_count(const int* __restrict__ u, const int* __restrict__ v,
                        int* __restrict__ cnt, int N, int E){
  int e = blockIdx.x*256 + threadIdx.x;
  if(e < E){
    atomicAdd(&cnt[v[e]], 1);
    atomicAdd(&cnt[N + u[e]], 1);
  }
}

__global__ void k_scan1(const int* __restrict__ cnt, int* __restrict__ part, int M){
  __shared__ int sm[256];
  int i = blockIdx.x*256 + threadIdx.x;
  sm[threadIdx.x] = (i < M) ? cnt[i] : 0;
  __syncthreads();
  for(int s = 128; s > 0; s >>= 1){
    if(threadIdx.x < s) sm[threadIdx.x] += sm[threadIdx.x + s];
    __syncthreads();
  }
  if(threadIdx.x == 0) part[blockIdx.x] = sm[0];
}

__global__ void k_scan2(int* __restrict__ part, int nb){
  __shared__ int sm[1024];
  int t = threadIdx.x;
  int orig = (t < nb) ? part[t] : 0;
  sm[t] = orig;
  __syncthreads();
  for(int off = 1; off < 1024; off <<= 1){
    int add = (t >= off) ? sm[t - off] : 0;
    __syncthreads();
    sm[t] += add;
    __syncthreads();
  }
  if(t < nb) part[t] = sm[t] - orig;  // exclusive prefix
}

__global__ void k_scan3(int* __restrict__ cnt, const int* __restrict__ part,
                        int* __restrict__ cur, int M, int total){
  __shared__ int sm[256];
  int t = threadIdx.x;
  int i = blockIdx.x*256 + t;
  int orig = (i < M) ? cnt[i] : 0;
  sm[t] = orig;
  __syncthreads();
  for(int off = 1; off < 256; off <<= 1){
    int add = (t >= off) ? sm[t - off] : 0;
    __syncthreads();
    sm[t] += add;
    __syncthreads();
  }
  if(i < M){
    int excl = part[blockIdx.x] + sm[t] - orig;
    cnt[i] = excl;
    cur[i] = excl;
  }
  if(i == 0) cnt[M] = total;
}

// rows[p] = edge id (for k_einout); srcs[p] = opposite endpoint (for k_aggr).
__global__ void k_fill(const int* __restrict__ u, const int* __restrict__ v,
                       int* __restrict__ cur, int* __restrict__ rows,
                       int* __restrict__ srcs, int N, int E){
  int e = blockIdx.x*256 + threadIdx.x;
  if(e < E){
    int uu = u[e], vv = v[e];
    int p = atomicAdd(&cur[vv], 1);     rows[p] = e; srcs[p] = uu;
    int q = atomicAdd(&cur[N + uu], 1); rows[q] = e; srcs[q] = vv;
  }
}

// ---------------- round-constant edge-feature sums ----------------
__global__ void k_einout(const float* __restrict__ ev, const int* __restrict__ off,
                         const int* __restrict__ rows,
                         float* __restrict__ Ein, float* __restrict__ Eout, int N){
  int n = (blockIdx.x*blockDim.x + threadIdx.x) >> 6;
  int lane = threadIdx.x & 63;
  if(n >= N) return;
  int t = lane & 15, s = lane >> 4;
  float a = 0.f;
  int p1 = off[n+1];
  for(int p = off[n] + s; p < p1; p += 4) a += ev[rows[p]*ES16 + t];
  a += __shfl_xor(a, 16, 64);
  a += __shfl_xor(a, 32, 64);
  if(lane < 16) Ein[n*ES16 + lane] = a;
  float b = 0.f;
  p1 = off[N+n+1];
  for(int p = off[N+n] + s; p < p1; p += 4) b += ev[rows[p]*ES16 + t];
  b += __shfl_xor(b, 16, 64);
  b += __shfl_xor(b, 32, 64);
  if(lane < 16) Eout[n*ES16 + lane] = b;
}

// ---------------- per-round sparse aggregation ----------------
__global__ void k_aggr(const float* __restrict__ h, const int* __restrict__ off,
                       const int* __restrict__ srcs,
                       float* __restrict__ Sin, float* __restrict__ Sout, int N){
  int gw = (blockIdx.x*blockDim.x + threadIdx.x) >> 6;
  int lane = threadIdx.x & 63;
  if(gw >= 2*N) return;
  int p = off[gw], p1 = off[gw+1];
  float sA = 0.f, sB = 0.f;
  for(; p + 4 <= p1; p += 4){
    int s0 = srcs[p], s1 = srcs[p+1], s2 = srcs[p+2], s3 = srcs[p+3];
    float a = h[(size_t)s0*D64 + lane];
    float b = h[(size_t)s1*D64 + lane];
    float c = h[(size_t)s2*D64 + lane];
    float d = h[(size_t)s3*D64 + lane];
    sA += a + b; sB += c + d;
  }
  for(; p < p1; ++p) sA += h[(size_t)srcs[p]*D64 + lane];
  float s = sA + sB;
  if(gw < N) Sin[(size_t)gw*D64 + lane] = s;
  else       Sout[(size_t)(gw-N)*D64 + lane] = s;
}

// ---------------- fused node transform + GRU ----------------
// 512 threads = 8 waves per 64-node tile.
// LDS layout TRANSPOSED vs earlier rounds: xT[node][k], row stride 196 floats
// (odd float4 count -> lane*49 % 8 == lane % 8 -> ds_read_b128 conflict-free).
// k regions: 0..63 Sin / 64..127 h / 128..191 Sout; after phase A the Sin/Sout
// regions are overwritten with agg (low/high). All compute-loop x reads are
// ds_read_b128 (96/wave vs 384 b32 in round 7 -> DS pipe cycles ~halved).
// wv uniform via readfirstlane -> weights/biases are s_load (SGPR operands).
// NOTE: plain __launch_bounds__(512) — a (512,6) clamp forced VGPR=40 + ~1 GB
// scratch spill (round-3 counters). Do not re-add.
__global__ __launch_bounds__(512) void k34_fused(
    const float* __restrict__ h, const float* __restrict__ Sin,
    const float* __restrict__ Sout, const float* __restrict__ Ein,
    const float* __restrict__ Eout, const int* __restrict__ off,
    const float* __restrict__ Wef, const float* __restrict__ bef,
    const float* __restrict__ Wer, const float* __restrict__ ber,
    const float* __restrict__ Wih, const float* __restrict__ Whh,
    const float* __restrict__ bih, const float* __restrict__ bhh,
    float* __restrict__ hnext, int N){
  __shared__ float xT[64][XSTR];
  const int lane = threadIdx.x & 63;
  const int wv   = __builtin_amdgcn_readfirstlane(threadIdx.x >> 6);
  const int base = blockIdx.x * 64;
  // staging: row = node-in-tile, col = k (lanes span k -> consecutive banks)
  for(int ii = 0; ii < 8; ++ii){
    int i = wv*8 + ii;
    int n = base + i; if(n >= N) n = N - 1;
    xT[i][lane]       = Sin[n*D64 + lane];
    xT[i][64+lane]    = h[n*D64 + lane];
    xT[i][128+lane]   = Sout[n*D64 + lane];
  }
  __syncthreads();
  int node = base + lane; if(node >= N) node = N - 1;
  const float fi = (float)(off[node+1] - off[node]);
  const float fo = (float)(off[N+node+1] - off[N+node]);
  float4 xi0 = *(const float4*)(Ein  + node*ES16 + 0);
  float4 xi1 = *(const float4*)(Ein  + node*ES16 + 4);
  float4 xi2 = *(const float4*)(Ein  + node*ES16 + 8);
  float4 xi3 = *(const float4*)(Ein  + node*ES16 + 12);
  float4 xo0 = *(const float4*)(Eout + node*ES16 + 0);
  float4 xo1 = *(const float4*)(Eout + node*ES16 + 4);
  float4 xo2 = *(const float4*)(Eout + node*ES16 + 8);
  float4 xo3 = *(const float4*)(Eout + node*ES16 + 12);

  const int jbase = wv*16;
  float acc[16];
  #pragma unroll
  for(int jj = 0; jj < 16; ++jj){
    int j = jbase + jj;
    acc[jj] = fi*bef[j] + fo*ber[j];
  }
  // Sin block: Wef cols 0..63  (x = b128 from own row)
  for(int k4 = 0; k4 < 16; ++k4){
    float4 x = *(const float4*)&xT[lane][k4*4];
    #pragma unroll
    for(int jj = 0; jj < 16; ++jj){
      float4 w = *(const float4*)(Wef + (jbase+jj)*144 + k4*4);
      acc[jj] = fmaf(w.x,x.x,fmaf(w.y,x.y,fmaf(w.z,x.z,fmaf(w.w,x.w,acc[jj]))));
    }
  }
  // h block: Wef cols 64..127 (xfi) and Wer cols 0..63 (xfo) share one b128 read
  for(int k4 = 0; k4 < 16; ++k4){
    float4 hx = *(const float4*)&xT[lane][64 + k4*4];
    float f0 = fi*hx.x, f1 = fi*hx.y, f2 = fi*hx.z, f3 = fi*hx.w;
    float r0 = fo*hx.x, r1 = fo*hx.y, r2 = fo*hx.z, r3 = fo*hx.w;
    for(int jh = 0; jh < 2; ++jh){
      #pragma unroll
      for(int jx = 0; jx < 8; ++jx){
        int jj = jh*8 + jx;
        int j = jbase + jj;
        float4 wf = *(const float4*)(Wef + j*144 + 64 + k4*4);
        float4 wr = *(const float4*)(Wer + j*144 + k4*4);
        acc[jj] = fmaf(wf.x,f0,fmaf(wf.y,f1,fmaf(wf.z,f2,fmaf(wf.w,f3,acc[jj]))));
        acc[jj] = fmaf(wr.x,r0,fmaf(wr.y,r1,fmaf(wr.z,r2,fmaf(wr.w,r3,acc[jj]))));
      }
    }
  }
  // E blocks (register-resident x, scalar weights)
  for(int jh = 0; jh < 2; ++jh){
    #pragma unroll
    for(int jx = 0; jx < 8; ++jx){
      int jj = jh*8 + jx;
      int j = jbase + jj;
      const float4* wfp = (const float4*)(Wef + j*144 + 128);
      const float4* wrp = (const float4*)(Wer + j*144 + 128);
      float4 wf, wr;
      wf = wfp[0]; wr = wrp[0];
      acc[jj] = fmaf(wf.x,xi0.x,fmaf(wf.y,xi0.y,fmaf(wf.z,xi0.z,fmaf(wf.w,xi0.w,acc[jj]))));
      acc[jj] = fmaf(wr.x,xo0.x,fmaf(wr.y,xo0.y,fmaf(wr.z,xo0.z,fmaf(wr.w,xo0.w,acc[jj]))));
      wf = wfp[1]; wr = wrp[1];
      acc[jj] = fmaf(wf.x,xi1.x,fmaf(wf.y,xi1.y,fmaf(wf.z,xi1.z,fmaf(wf.w,xi1.w,acc[jj]))));
      acc[jj] = fmaf(wr.x,xo1.x,fmaf(wr.y,xo1.y,fmaf(wr.z,xo1.z,fmaf(wr.w,xo1.w,acc[jj]))));
      wf = wfp[2]; wr = wrp[2];
      acc[jj] = fmaf(wf.x,xi2.x,fmaf(wf.y,xi2.y,fmaf(wf.z,xi2.z,fmaf(wf.w,xi2.w,acc[jj]))));
      acc[jj] = fmaf(wr.x,xo2.x,fmaf(wr.y,xo2.y,fmaf(wr.z,xo2.z,fmaf(wr.w,xo2.w,acc[jj]))));
      wf = wfp[3]; wr = wrp[3];
      acc[jj] = fmaf(wf.x,xi3.x,fmaf(wf.y,xi3.y,fmaf(wf.z,xi3.z,fmaf(wf.w,xi3.w,acc[jj]))));
      acc[jj] = fmaf(wr.x,xo3.x,fmaf(wr.y,xo3.y,fmaf(wr.z,xo3.z,fmaf(wr.w,xo3.w,acc[jj]))));
    }
  }
  // Sout block: Wer cols 64..127
  for(int k4 = 0; k4 < 16; ++k4){
    float4 x = *(const float4*)&xT[lane][128 + k4*4];
    #pragma unroll
    for(int jj = 0; jj < 16; ++jj){
      float4 w = *(const float4*)(Wer + (jbase+jj)*144 + 64 + k4*4);
      acc[jj] = fmaf(w.x,x.x,fmaf(w.y,x.y,fmaf(w.z,x.z,fmaf(w.w,x.w,acc[jj]))));
    }
  }

  // ---- agg -> LDS (overwrite Sin/Sout k-regions); h region stays live ----
  __syncthreads();   // all waves done READING Sin/Sout regions
  {
    // agg col c = jbase+jj; c<64 -> k=c (old Sin); c>=64 -> k=128+(c-64) (old Sout)
    const int krow = (jbase < 64) ? jbase : (64 + jbase);   // wave-uniform
    #pragma unroll
    for(int q = 0; q < 4; ++q){
      float4 v; v.x = acc[q*4+0]; v.y = acc[q*4+1]; v.z = acc[q*4+2]; v.w = acc[q*4+3];
      *(float4*)&xT[lane][krow + q*4] = v;   // b128, conflict-free
    }
  }
  __syncthreads();

  // ---- Phase B: GRU, single pass, 8 q-outputs per wave, b128 x reads ----
  const int qt = wv;
  float aR[8], aZ[8], aN[8], aH[8];
  #pragma unroll
  for(int i = 0; i < 8; ++i){
    int q = qt*8 + i;
    aR[i] = bih[q]      + bhh[q];
    aZ[i] = bih[64+q]   + bhh[64+q];
    aN[i] = bih[128+q];
    aH[i] = bhh[128+q];
  }
  // W_ih x agg, k = 0..63 (LDS k 0..63)
  for(int k4 = 0; k4 < 16; ++k4){
    float4 x = *(const float4*)&xT[lane][k4*4];
    for(int ih = 0; ih < 2; ++ih){
      #pragma unroll
      for(int ix = 0; ix < 4; ++ix){
        int i = ih*4 + ix;
        int q = qt*8 + i;
        float4 wr = *(const float4*)(Wih + q*128       + k4*4);
        float4 wz = *(const float4*)(Wih + (64+q)*128  + k4*4);
        float4 wn = *(const float4*)(Wih + (128+q)*128 + k4*4);
        aR[i] = fmaf(wr.x,x.x,fmaf(wr.y,x.y,fmaf(wr.z,x.z,fmaf(wr.w,x.w,aR[i]))));
        aZ[i] = fmaf(wz.x,x.x,fmaf(wz.y,x.y,fmaf(wz.z,x.z,fmaf(wz.w,x.w,aZ[i]))));
        aN[i] = fmaf(wn.x,x.x,fmaf(wn.y,x.y,fmaf(wn.z,x.z,fmaf(wn.w,x.w,aN[i]))));
      }
    }
  }
  // W_ih x agg, k = 64..127 (LDS k 128..191)
  for(int k4 = 0; k4 < 16; ++k4){
    float4 x = *(const float4*)&xT[lane][128 + k4*4];
    for(int ih = 0; ih < 2; ++ih){
      #pragma unroll
      for(int ix = 0; ix < 4; ++ix){
        int i = ih*4 + ix;
        int q = qt*8 + i;
        float4 wr = *(const float4*)(Wih + q*128       + 64 + k4*4);
        float4 wz = *(const float4*)(Wih + (64+q)*128  + 64 + k4*4);
        float4 wn = *(const float4*)(Wih + (128+q)*128 + 64 + k4*4);
        aR[i] = fmaf(wr.x,x.x,fmaf(wr.y,x.y,fmaf(wr.z,x.z,fmaf(wr.w,x.w,aR[i]))));
        aZ[i] = fmaf(wz.x,x.x,fmaf(wz.y,x.y,fmaf(wz.z,x.z,fmaf(wz.w,x.w,aZ[i]))));
        aN[i] = fmaf(wn.x,x.x,fmaf(wn.y,x.y,fmaf(wn.z,x.z,fmaf(wn.w,x.w,aN[i]))));
      }
    }
  }
  // W_hh x h, k = 0..63 (LDS k 64..127)
  for(int k4 = 0; k4 < 16; ++k4){
    float4 x = *(const float4*)&xT[lane][64 + k4*4];
    for(int ih = 0; ih < 2; ++ih){
      #pragma unroll
      for(int ix = 0; ix < 4; ++ix){
        int i = ih*4 + ix;
        int q = qt*8 + i;
        float4 wr = *(const float4*)(Whh + q*64       + k4*4);
        float4 wz = *(const float4*)(Whh + (64+q)*64  + k4*4);
        float4 wh = *(const float4*)(Whh + (128+q)*64 + k4*4);
        aR[i] = fmaf(wr.x,x.x,fmaf(wr.y,x.y,fmaf(wr.z,x.z,fmaf(wr.w,x.w,aR[i]))));
        aZ[i] = fmaf(wz.x,x.x,fmaf(wz.y,x.y,fmaf(wz.z,x.z,fmaf(wz.w,x.w,aZ[i]))));
        aH[i] = fmaf(wh.x,x.x,fmaf(wh.y,x.y,fmaf(wh.z,x.z,fmaf(wh.w,x.w,aH[i]))));
      }
    }
  }
  float hout[8];
  {
    float4 hq0 = *(const float4*)&xT[lane][64 + qt*8];
    float4 hq1 = *(const float4*)&xT[lane][64 + qt*8 + 4];
    float hqv[8] = {hq0.x,hq0.y,hq0.z,hq0.w,hq1.x,hq1.y,hq1.z,hq1.w};
    #pragma unroll
    for(int i = 0; i < 8; ++i){
      float r = sigf(aR[i]);
      float z = sigf(aZ[i]);
      float nn = tanhfast(aN[i] + r*aH[i]);
      hout[i] = (1.f - z)*nn + z*hqv[i];
    }
  }
  __syncthreads();   // all waves done reading agg/h -> reuse k 0..63 as h'
  {
    float4 v0; v0.x=hout[0]; v0.y=hout[1]; v0.z=hout[2]; v0.w=hout[3];
    float4 v1; v1.x=hout[4]; v1.y=hout[5]; v1.z=hout[6]; v1.w=hout[7];
    *(float4*)&xT[lane][qt*8]     = v0;    // h'[node=lane][feature qt*8..]
    *(float4*)&xT[lane][qt*8 + 4] = v1;
  }
  __syncthreads();
  for(int ii = 0; ii < 8; ++ii){
    int i = wv*8 + ii;
    int n = base + i;
    if(n < N) hnext[n*D64 + lane] = xT[i][lane];
  }
}

// ---------------- gated readout: register-accumulated partials, no atomics ----------------
__global__ __launch_bounds__(512) void k5_read(
    const float* __restrict__ h, const float* __restrict__ Wfm,
    const float* __restrict__ bfm, const float* __restrict__ Wgm,
    const float* __restrict__ bgm, float* __restrict__ partials, int N, int nT){
  __shared__ float xT[64][67];
  const int lane = threadIdx.x & 63;
  const int wv   = __builtin_amdgcn_readfirstlane(threadIdx.x >> 6);
  float acc[2][8];
  #pragma unroll
  for(int t = 0; t < 2; ++t)
    #pragma unroll
    for(int jj = 0; jj < 8; ++jj) acc[t][jj] = 0.f;

  for(int tile = blockIdx.x; tile < nT; tile += NB5){
    const int base = tile * 64;
    __syncthreads();
    for(int ii = 0; ii < 8; ++ii){
      int i = wv*8 + ii;
      int n = base + i; if(n >= N) n = N - 1;
      xT[lane][i] = h[n*D64 + lane];
    }
    __syncthreads();
    const bool valid = (base + lane) < N;
    for(int t = 0; t < 2; ++t){
      const int jt = wv + t*8;
      float aF[8], aG[8];
      #pragma unroll
      for(int jj = 0; jj < 8; ++jj){
        int j = jt*8 + jj;
        aF[jj] = bfm[j]; aG[jj] = bgm[j];
      }
      #pragma unroll 2
      for(int k4 = 0; k4 < 16; ++k4){
        float x0 = xT[k4*4+0][lane];
        float x1 = xT[k4*4+1][lane];
        float x2 = xT[k4*4+2][lane];
        float x3 = xT[k4*4+3][lane];
        #pragma unroll
        for(int jj = 0; jj < 8; ++jj){
          int j = jt*8 + jj;
          float4 wf = *(const float4*)(Wfm + j*64 + k4*4);
          float4 wg = *(const float4*)(Wgm + j*64 + k4*4);
          aF[jj] = fmaf(wf.x,x0,fmaf(wf.y,x1,fmaf(wf.z,x2,fmaf(wf.w,x3,aF[jj]))));
          aG[jj] = fmaf(wg.x,x0,fmaf(wg.y,x1,fmaf(wg.z,x2,fmaf(wg.w,x3,aG[jj]))));
        }
      }
      if(valid){
        #pragma unroll
        for(int jj = 0; jj < 8; ++jj)
          acc[t][jj] += aF[jj] * sigf(aG[jj]);
      }
    }
  }
  #pragma unroll
  for(int t = 0; t < 2; ++t)
    for(int jj = 0; jj < 8; ++jj){
      float val = acc[t][jj];
      #pragma unroll
      for(int o = 32; o > 0; o >>= 1) val += __shfl_xor(val, o, 64);
      if(lane == 0) partials[blockIdx.x*128 + (wv + t*8)*8 + jj] = val;
    }
}

__global__ void k6_dec(const float* __restrict__ partials, int nb,
                       const float* __restrict__ h,
                       const float* __restrict__ Wdec, const float* __restrict__ bdec,
                       const int* __restrict__ tgt, float* __restrict__ out){
  __shared__ float sm[256];
  int t = threadIdx.x;
  float v = 0.f;
  if(t < 128){
    float s0 = 0.f, s1 = 0.f, s2 = 0.f, s3 = 0.f;
    for(int b = 0; b + 4 <= nb; b += 4){
      s0 += partials[(b+0)*128 + t];
      s1 += partials[(b+1)*128 + t];
      s2 += partials[(b+2)*128 + t];
      s3 += partials[(b+3)*128 + t];
    }
    v = ((s0 + s1) + (s2 + s3)) * Wdec[t];
  } else if(t < 192){
    v = h[tgt[0]*D64 + (t - 128)] * Wdec[t];
  }
  sm[t] = v;
  __syncthreads();
  for(int s = 128; s > 0; s >>= 1){
    if(t < s) sm[t] += sm[t + s];
    __syncthreads();
  }
  if(t == 0) out[0] = sm[0] + bdec[0];
}

extern "C" void kernel_launch(void* const* d_in, const int* in_sizes, int n_in,
                              void* d_out, int out_size, void* d_ws, size_t ws_size,
                              hipStream_t stream){
  const float* nodev = (const float*)d_in[0];
  const float* ev    = (const float*)d_in[1];
  const float* Wef   = (const float*)d_in[2];
  const float* bef   = (const float*)d_in[3];
  const float* Wer   = (const float*)d_in[4];
  const float* ber   = (const float*)d_in[5];
  const float* Wih   = (const float*)d_in[6];
  const float* Whh   = (const float*)d_in[7];
  const float* bih   = (const float*)d_in[8];
  const float* bhh   = (const float*)d_in[9];
  const float* Wfm   = (const float*)d_in[10];
  const float* bfm   = (const float*)d_in[11];
  const float* Wgm   = (const float*)d_in[12];
  const float* bgm   = (const float*)d_in[13];
  const float* Wdec  = (const float*)d_in[14];
  const float* bdec  = (const float*)d_in[15];
  const int* uidx    = (const int*)d_in[16];
  const int* vidx    = (const int*)d_in[17];
  const int* tgt     = (const int*)d_in[18];

  const int N = in_sizes[0] / 64;
  const int E = in_sizes[16];
  const int R = in_sizes[2] / (128*144);

  char* w = (char*)d_ws;
  auto alloc = [&](size_t bytes) -> void* {
    void* p = (void*)w;
    w += (bytes + 255) & ~(size_t)255;
    return p;
  };
  int* off       = (int*)alloc(((size_t)2*N + 1) * 4);
  int* cur       = (int*)alloc((size_t)2*N * 4);
  int* rows      = (int*)alloc((size_t)2*E * 4);
  int* srcs      = (int*)alloc((size_t)2*E * 4);
  int* part      = (int*)alloc(4096 * 4);
  float* Ein     = (float*)alloc((size_t)N*16*4);
  float* Eout    = (float*)alloc((size_t)N*16*4);
  float* Sin     = (float*)alloc((size_t)N*64*4);
  float* Sout    = (float*)alloc((size_t)N*64*4);
  float* hA      = (float*)alloc((size_t)N*64*4);
  float* hB      = (float*)alloc((size_t)N*64*4);
  float* partial = (float*)alloc((size_t)NB5*128*4);

  hipMemsetAsync(off, 0, ((size_t)2*N+1)*4, stream);

  int eb = (E + 255)/256;
  k_count<<<eb, 256, 0, stream>>>(uidx, vidx, off, N, E);
  int M = 2*N;
  int nb = (M + 255)/256;
  k_scan1<<<nb, 256, 0, stream>>>(off, part, M);
  k_scan2<<<1, 1024, 0, stream>>>(part, nb);
  k_scan3<<<nb, 256, 0, stream>>>(off, part, cur, M, 2*E);
  k_fill<<<eb, 256, 0, stream>>>(uidx, vidx, cur, rows, srcs, N, E);
  int wb = (N + 3)/4;
  k_einout<<<wb, 256, 0, stream>>>(ev, off, rows, Ein, Eout, N);

  int nT = (N + 63)/64;
  int ab = (2*N + 3)/4;
  const float* hcur = nodev;
  float* bufs[2] = {hA, hB};
  for(int r = 0; r < R; ++r){
    k_aggr<<<ab, 256, 0, stream>>>(hcur, off, srcs, Sin, Sout, N);
    float* hn = bufs[r & 1];
    k34_fused<<<nT, 512, 0, stream>>>(hcur, Sin, Sout, Ein, Eout, off,
                                      Wef + (size_t)r*128*144, bef + r*128,
                                      Wer + (size_t)r*128*144, ber + r*128,
                                      Wih + (size_t)r*192*128, Whh + (size_t)r*192*64,
                                      bih + r*192, bhh + r*192, hn, N);
    hcur = hn;
  }
  k5_read<<<NB5, 512, 0, stream>>>(hcur, Wfm, bfm, Wgm, bgm, partial, N, nT);
  k6_dec<<<1, 256, 0, stream>>>(partial, NB5, hcur, Wdec, bdec, tgt, (float*)d_out);
}

// Round 10
// 631.767 us; speedup vs baseline: 5.4696x; 1.7879x over previous
//
#include <hip/hip_runtime.h>
#include <math.h>

#define D64 64
#define ES16 16
#define NB5 256

typedef unsigned short u16;
typedef _Float16 half8 __attribute__((ext_vector_type(8)));
typedef __attribute__((ext_vector_type(4))) float f32x4;

// K layout, phase A (K=320, 10 k-tiles):
//  [0:64) Sin | [64:128) fi*h | [128:144) Ein | [144] fi | [145:160) 0
//  [160:224) fo*h | [224:288) Sout | [288:304) Eout | [304] fo | [305:320) 0
// B rows j (128): Wef cols for k<144, bef at 144, Wer cols at 160.., ber at 304.
// K layout, phase B (K=256, 8 k-tiles):
//  [0:128) agg | [128] 1.0 | [129:160) 0 | [160:224) h | [224] 1.0 | [225:256) 0
// B rows q (192 = r|z|n gates): Wih cols k<128, bih at 128, Whh at 160.., bhh at 224.
// n-gate: acc_nI over k-tiles 0..4 (gi_n + bih_n), acc_nH over 5..7 (gh_n + bhh_n).
// fp16 (not bf16): same fragment geometry, 8x smaller rounding — round-9's
// absmax 3.0 was pure bf16 accumulation error (structure verified).

__device__ __forceinline__ float sigf(float x){ return 1.0f/(1.0f + __expf(-x)); }
__device__ __forceinline__ float tanhfast(float x){ return 2.0f*sigf(2.0f*x) - 1.0f; }
__device__ __forceinline__ u16 f2h(float f){             // RNE fp32->fp16
  _Float16 h = (_Float16)f;
  u16 r; __builtin_memcpy(&r, &h, 2); return r;
}

// ---------------- CSR build ----------------
__global__ void k_count(const int* __restrict__ u, const int* __restrict__ v,
                        int* __restrict__ cnt, int N, int E){
  int e = blockIdx.x*256 + threadIdx.x;
  if(e < E){
    atomicAdd(&cnt[v[e]], 1);
    atomicAdd(&cnt[N + u[e]], 1);
  }
}

__global__ void k_scan1(const int* __restrict__ cnt, int* __restrict__ part, int M){
  __shared__ int sm[256];
  int i = blockIdx.x*256 + threadIdx.x;
  sm[threadIdx.x] = (i < M) ? cnt[i] : 0;
  __syncthreads();
  for(int s = 128; s > 0; s >>= 1){
    if(threadIdx.x < s) sm[threadIdx.x] += sm[threadIdx.x + s];
    __syncthreads();
  }
  if(threadIdx.x == 0) part[blockIdx.x] = sm[0];
}

__global__ void k_scan2(int* __restrict__ part, int nb){
  __shared__ int sm[1024];
  int t = threadIdx.x;
  int orig = (t < nb) ? part[t] : 0;
  sm[t] = orig;
  __syncthreads();
  for(int off = 1; off < 1024; off <<= 1){
    int add = (t >= off) ? sm[t - off] : 0;
    __syncthreads();
    sm[t] += add;
    __syncthreads();
  }
  if(t < nb) part[t] = sm[t] - orig;  // exclusive prefix
}

__global__ void k_scan3(int* __restrict__ cnt, const int* __restrict__ part,
                        int* __restrict__ cur, int M, int total){
  __shared__ int sm[256];
  int t = threadIdx.x;
  int i = blockIdx.x*256 + t;
  int orig = (i < M) ? cnt[i] : 0;
  sm[t] = orig;
  __syncthreads();
  for(int off = 1; off < 256; off <<= 1){
    int add = (t >= off) ? sm[t - off] : 0;
    __syncthreads();
    sm[t] += add;
    __syncthreads();
  }
  if(i < M){
    int excl = part[blockIdx.x] + sm[t] - orig;
    cnt[i] = excl;
    cur[i] = excl;
  }
  if(i == 0) cnt[M] = total;
}

__global__ void k_fill(const int* __restrict__ u, const int* __restrict__ v,
                       int* __restrict__ cur, int* __restrict__ rows,
                       int* __restrict__ srcs, int N, int E){
  int e = blockIdx.x*256 + threadIdx.x;
  if(e < E){
    int uu = u[e], vv = v[e];
    int p = atomicAdd(&cur[vv], 1);     rows[p] = e; srcs[p] = uu;
    int q = atomicAdd(&cur[N + uu], 1); rows[q] = e; srcs[q] = vv;
  }
}

// ---------------- round-constant edge-feature sums ----------------
__global__ void k_einout(const float* __restrict__ ev, const int* __restrict__ off,
                         const int* __restrict__ rows,
                         float* __restrict__ Ein, float* __restrict__ Eout, int N){
  int n = (blockIdx.x*blockDim.x + threadIdx.x) >> 6;
  int lane = threadIdx.x & 63;
  if(n >= N) return;
  int t = lane & 15, s = lane >> 4;
  float a = 0.f;
  int p1 = off[n+1];
  for(int p = off[n] + s; p < p1; p += 4) a += ev[rows[p]*ES16 + t];
  a += __shfl_xor(a, 16, 64);
  a += __shfl_xor(a, 32, 64);
  if(lane < 16) Ein[n*ES16 + lane] = a;
  float b = 0.f;
  p1 = off[N+n+1];
  for(int p = off[N+n] + s; p < p1; p += 4) b += ev[rows[p]*ES16 + t];
  b += __shfl_xor(b, 16, 64);
  b += __shfl_xor(b, 32, 64);
  if(lane < 16) Eout[n*ES16 + lane] = b;
}

// ---------------- per-round sparse aggregation ----------------
__global__ void k_aggr(const float* __restrict__ h, const int* __restrict__ off,
                       const int* __restrict__ srcs,
                       float* __restrict__ Sin, float* __restrict__ Sout, int N){
  int gw = (blockIdx.x*blockDim.x + threadIdx.x) >> 6;
  int lane = threadIdx.x & 63;
  if(gw >= 2*N) return;
  int p = off[gw], p1 = off[gw+1];
  float sA = 0.f, sB = 0.f;
  for(; p + 4 <= p1; p += 4){
    int s0 = srcs[p], s1 = srcs[p+1], s2 = srcs[p+2], s3 = srcs[p+3];
    float a = h[(size_t)s0*D64 + lane];
    float b = h[(size_t)s1*D64 + lane];
    float c = h[(size_t)s2*D64 + lane];
    float d = h[(size_t)s3*D64 + lane];
    sA += a + b; sB += c + d;
  }
  for(; p < p1; ++p) sA += h[(size_t)srcs[p]*D64 + lane];
  float s = sA + sB;
  if(gw < N) Sin[(size_t)gw*D64 + lane] = s;
  else       Sout[(size_t)(gw-N)*D64 + lane] = s;
}

// ---------------- weight -> fp16 B-fragment preprocess ----------------
// Fragment layout (v_mfma_f32_16x16x32_f16 B operand): col j = lane&15,
// k = (lane>>4)*8 + e, e = 0..7. One block = one (round, ntile, ktile) frag:
// 64 lanes x 8 fp16 = 1 KB, stored contiguously for coalesced dwordx4 reads.
__global__ void k_preA(const float* __restrict__ Wef, const float* __restrict__ bef,
                       const float* __restrict__ Wer, const float* __restrict__ ber,
                       u16* __restrict__ bA){
  int b = blockIdx.x;          // r*80 + nt*10 + kt
  int r = b / 80, t = b % 80;
  int nt = t / 10, kt = t % 10;
  int lane = threadIdx.x;
  int j = nt*16 + (lane & 15);
  int ks0 = kt*32 + (lane >> 4)*8;
  const float* wef = Wef + (size_t)r*128*144;
  const float* wer = Wer + (size_t)r*128*144;
  u16 v[8];
  #pragma unroll
  for(int e = 0; e < 8; ++e){
    int ks = ks0 + e;
    float val;
    if(ks < 144)       val = wef[j*144 + ks];
    else if(ks == 144) val = bef[r*128 + j];
    else if(ks < 160)  val = 0.f;
    else if(ks < 304)  val = wer[j*144 + (ks - 160)];
    else if(ks == 304) val = ber[r*128 + j];
    else               val = 0.f;
    v[e] = f2h(val);
  }
  u16* dst = bA + ((size_t)b*64 + lane)*8;
  #pragma unroll
  for(int e = 0; e < 8; ++e) dst[e] = v[e];
}

__global__ void k_preB(const float* __restrict__ Wih, const float* __restrict__ Whh,
                       const float* __restrict__ bih, const float* __restrict__ bhh,
                       u16* __restrict__ bB){
  int b = blockIdx.x;          // r*96 + nt*8 + kt
  int r = b / 96, t = b % 96;
  int nt = t / 8, kt = t % 8;
  int lane = threadIdx.x;
  int q = nt*16 + (lane & 15);
  int ks0 = kt*32 + (lane >> 4)*8;
  const float* wih = Wih + (size_t)r*192*128;
  const float* whh = Whh + (size_t)r*192*64;
  u16 v[8];
  #pragma unroll
  for(int e = 0; e < 8; ++e){
    int ks = ks0 + e;
    float val;
    if(ks < 128)       val = wih[q*128 + ks];
    else if(ks == 128) val = bih[r*192 + q];
    else if(ks < 160)  val = 0.f;
    else if(ks < 224)  val = whh[q*64 + (ks - 160)];
    else if(ks == 224) val = bhh[r*192 + q];
    else               val = 0.f;
    v[e] = f2h(val);
  }
  u16* dst = bB + ((size_t)b*64 + lane)*8;
  #pragma unroll
  for(int e = 0; e < 8; ++e) dst[e] = v[e];
}

// ---------------- fused node transform + GRU via MFMA (fp16) ----------------
// 512 threads = 8 waves per 64-node tile. Phase A: wave wv owns n-tile wv
// (agg cols wv*16..+15), all 4 m-tiles, 10 k-tiles -> 40 mfma. Phase B: wave
// owns 2 (m-tile, gate-triple) units -> 48 mfma; r/z/n for a given q are
// lane-local so the GRU combine needs no cross-lane traffic.
// LDS strides are odd multiples of 16 B -> conflict-free ds_read_b128.
__global__ __launch_bounds__(512) void k34_mfma(
    const float* __restrict__ h, const float* __restrict__ Sin,
    const float* __restrict__ Sout, const float* __restrict__ Ein,
    const float* __restrict__ Eout, const int* __restrict__ off,
    const u16* __restrict__ bA, const u16* __restrict__ bB,
    float* __restrict__ hnext, int N){
  __shared__ u16 xA[64][328];   // 320 + pad -> 656 B = 41*16
  __shared__ u16 x2[64][264];   // 256 + pad -> 528 B = 33*16
  const int lane = threadIdx.x & 63;
  const int wv   = __builtin_amdgcn_readfirstlane(threadIdx.x >> 6);
  const int base = blockIdx.x * 64;

  // ---- staging: fp32 -> fp16 into LDS ----
  for(int ii = 0; ii < 8; ++ii){
    int i = wv*8 + ii;
    int n = base + i; if(n >= N) n = N - 1;
    float fi = (float)(off[n+1] - off[n]);
    float fo = (float)(off[N+n+1] - off[N+n]);
    float sv = Sin[(size_t)n*D64 + lane];
    float hv = h[(size_t)n*D64 + lane];
    float so = Sout[(size_t)n*D64 + lane];
    xA[i][lane]        = f2h(sv);
    xA[i][64 + lane]   = f2h(fi*hv);
    xA[i][160 + lane]  = f2h(fo*hv);
    xA[i][224 + lane]  = f2h(so);
    x2[i][160 + lane]  = f2h(hv);
    if(lane < 16){
      xA[i][128 + lane] = f2h(Ein[(size_t)n*ES16 + lane]);
      xA[i][288 + lane] = f2h(Eout[(size_t)n*ES16 + lane]);
    }
    if(lane == 0){
      xA[i][144] = f2h(fi); xA[i][304] = f2h(fo);
      x2[i][128] = 0x3C00;  x2[i][224] = 0x3C00;   // fp16 1.0
    }
    if(lane >= 1 && lane < 16){ xA[i][144 + lane] = 0; xA[i][304 + lane] = 0; }
    if(lane >= 1 && lane < 32){ x2[i][128 + lane] = 0; x2[i][224 + lane] = 0; }
  }
  __syncthreads();

  // ---- phase A: agg = x @ B_A^T ; wave n-tile = wv ----
  half8 bw[10];
  #pragma unroll
  for(int kt = 0; kt < 10; ++kt)
    bw[kt] = *(const half8*)(bA + ((size_t)(wv*10 + kt)*64 + lane)*8);

  f32x4 accA[4];
  const int arow = lane & 15;
  const int akof = (lane >> 4) * 8;
  #pragma unroll
  for(int m = 0; m < 4; ++m){
    f32x4 a = {0.f, 0.f, 0.f, 0.f};
    #pragma unroll
    for(int kt = 0; kt < 10; ++kt){
      half8 av = *(const half8*)&xA[m*16 + arow][kt*32 + akof];
      a = __builtin_amdgcn_mfma_f32_16x16x32_f16(av, bw[kt], a, 0, 0, 0);
    }
    accA[m] = a;
  }

  // ---- agg (fp16) -> x2[:, jb..jb+15]; C/D: col=lane&15, row=(lane>>4)*4+reg ----
  const int jb = wv * 16;
  #pragma unroll
  for(int m = 0; m < 4; ++m){
    #pragma unroll
    for(int reg = 0; reg < 4; ++reg){
      int nl = m*16 + (lane >> 4)*4 + reg;
      x2[nl][jb + (lane & 15)] = f2h(accA[m][reg]);
    }
  }
  __syncthreads();

  // ---- phase B: gates = x2 @ B_B^T ; 2 units/wave ----
  #pragma unroll
  for(int uu = 0; uu < 2; ++uu){
    const int unit = wv*2 + uu;
    const int mt  = unit >> 2;
    const int tri = unit & 3;
    f32x4 aR  = {0.f,0.f,0.f,0.f};
    f32x4 aZ  = {0.f,0.f,0.f,0.f};
    f32x4 aNi = {0.f,0.f,0.f,0.f};
    f32x4 aNh = {0.f,0.f,0.f,0.f};
    #pragma unroll
    for(int kt = 0; kt < 8; ++kt){
      half8 av = *(const half8*)&x2[mt*16 + arow][kt*32 + akof];
      half8 bR = *(const half8*)(bB + ((size_t)((tri    )*8 + kt)*64 + lane)*8);
      half8 bZ = *(const half8*)(bB + ((size_t)((tri + 4)*8 + kt)*64 + lane)*8);
      half8 bN = *(const half8*)(bB + ((size_t)((tri + 8)*8 + kt)*64 + lane)*8);
      aR = __builtin_amdgcn_mfma_f32_16x16x32_f16(av, bR, aR, 0, 0, 0);
      aZ = __builtin_amdgcn_mfma_f32_16x16x32_f16(av, bZ, aZ, 0, 0, 0);
      if(kt < 5) aNi = __builtin_amdgcn_mfma_f32_16x16x32_f16(av, bN, aNi, 0, 0, 0);
      else       aNh = __builtin_amdgcn_mfma_f32_16x16x32_f16(av, bN, aNh, 0, 0, 0);
    }
    const int q = tri*16 + (lane & 15);
    #pragma unroll
    for(int reg = 0; reg < 4; ++reg){
      int node = base + mt*16 + (lane >> 4)*4 + reg;
      float r  = sigf(aR[reg]);
      float z  = sigf(aZ[reg]);
      float nn = tanhfast(aNi[reg] + r*aNh[reg]);
      if(node < N){
        float hq = h[(size_t)node*D64 + q];
        hnext[(size_t)node*D64 + q] = (1.f - z)*nn + z*hq;
      }
    }
  }
}

// ---------------- gated readout: register-accumulated partials, no atomics ----------------
__global__ __launch_bounds__(512) void k5_read(
    const float* __restrict__ h, const float* __restrict__ Wfm,
    const float* __restrict__ bfm, const float* __restrict__ Wgm,
    const float* __restrict__ bgm, float* __restrict__ partials, int N, int nT){
  __shared__ float xT[64][67];
  const int lane = threadIdx.x & 63;
  const int wv   = __builtin_amdgcn_readfirstlane(threadIdx.x >> 6);
  float acc[2][8];
  #pragma unroll
  for(int t = 0; t < 2; ++t)
    #pragma unroll
    for(int jj = 0; jj < 8; ++jj) acc[t][jj] = 0.f;

  for(int tile = blockIdx.x; tile < nT; tile += NB5){
    const int base = tile * 64;
    __syncthreads();
    for(int ii = 0; ii < 8; ++ii){
      int i = wv*8 + ii;
      int n = base + i; if(n >= N) n = N - 1;
      xT[lane][i] = h[n*D64 + lane];
    }
    __syncthreads();
    const bool valid = (base + lane) < N;
    for(int t = 0; t < 2; ++t){
      const int jt = wv + t*8;
      float aF[8], aG[8];
      #pragma unroll
      for(int jj = 0; jj < 8; ++jj){
        int j = jt*8 + jj;
        aF[jj] = bfm[j]; aG[jj] = bgm[j];
      }
      #pragma unroll 2
      for(int k4 = 0; k4 < 16; ++k4){
        float x0 = xT[k4*4+0][lane];
        float x1 = xT[k4*4+1][lane];
        float x2 = xT[k4*4+2][lane];
        float x3 = xT[k4*4+3][lane];
        #pragma unroll
        for(int jj = 0; jj < 8; ++jj){
          int j = jt*8 + jj;
          float4 wf = *(const float4*)(Wfm + j*64 + k4*4);
          float4 wg = *(const float4*)(Wgm + j*64 + k4*4);
          aF[jj] = fmaf(wf.x,x0,fmaf(wf.y,x1,fmaf(wf.z,x2,fmaf(wf.w,x3,aF[jj]))));
          aG[jj] = fmaf(wg.x,x0,fmaf(wg.y,x1,fmaf(wg.z,x2,fmaf(wg.w,x3,aG[jj]))));
        }
      }
      if(valid){
        #pragma unroll
        for(int jj = 0; jj < 8; ++jj)
          acc[t][jj] += aF[jj] * sigf(aG[jj]);
      }
    }
  }
  #pragma unroll
  for(int t = 0; t < 2; ++t)
    for(int jj = 0; jj < 8; ++jj){
      float val = acc[t][jj];
      #pragma unroll
      for(int o = 32; o > 0; o >>= 1) val += __shfl_xor(val, o, 64);
      if(lane == 0) partials[blockIdx.x*128 + (wv + t*8)*8 + jj] = val;
    }
}

__global__ void k6_dec(const float* __restrict__ partials, int nb,
                       const float* __restrict__ h,
                       const float* __restrict__ Wdec, const float* __restrict__ bdec,
                       const int* __restrict__ tgt, float* __restrict__ out){
  __shared__ float sm[256];
  int t = threadIdx.x;
  float v = 0.f;
  if(t < 128){
    float s0 = 0.f, s1 = 0.f, s2 = 0.f, s3 = 0.f;
    for(int b = 0; b + 4 <= nb; b += 4){
      s0 += partials[(b+0)*128 + t];
      s1 += partials[(b+1)*128 + t];
      s2 += partials[(b+2)*128 + t];
      s3 += partials[(b+3)*128 + t];
    }
    v = ((s0 + s1) + (s2 + s3)) * Wdec[t];
  } else if(t < 192){
    v = h[tgt[0]*D64 + (t - 128)] * Wdec[t];
  }
  sm[t] = v;
  __syncthreads();
  for(int s = 128; s > 0; s >>= 1){
    if(t < s) sm[t] += sm[t + s];
    __syncthreads();
  }
  if(t == 0) out[0] = sm[0] + bdec[0];
}

extern "C" void kernel_launch(void* const* d_in, const int* in_sizes, int n_in,
                              void* d_out, int out_size, void* d_ws, size_t ws_size,
                              hipStream_t stream){
  const float* nodev = (const float*)d_in[0];
  const float* ev    = (const float*)d_in[1];
  const float* Wef   = (const float*)d_in[2];
  const float* bef   = (const float*)d_in[3];
  const float* Wer   = (const float*)d_in[4];
  const float* ber   = (const float*)d_in[5];
  const float* Wih   = (const float*)d_in[6];
  const float* Whh   = (const float*)d_in[7];
  const float* bih   = (const float*)d_in[8];
  const float* bhh   = (const float*)d_in[9];
  const float* Wfm   = (const float*)d_in[10];
  const float* bfm   = (const float*)d_in[11];
  const float* Wgm   = (const float*)d_in[12];
  const float* bgm   = (const float*)d_in[13];
  const float* Wdec  = (const float*)d_in[14];
  const float* bdec  = (const float*)d_in[15];
  const int* uidx    = (const int*)d_in[16];
  const int* vidx    = (const int*)d_in[17];
  const int* tgt     = (const int*)d_in[18];

  const int N = in_sizes[0] / 64;
  const int E = in_sizes[16];
  const int R = in_sizes[2] / (128*144);

  char* w = (char*)d_ws;
  auto alloc = [&](size_t bytes) -> void* {
    void* p = (void*)w;
    w += (bytes + 255) & ~(size_t)255;
    return p;
  };
  int* off       = (int*)alloc(((size_t)2*N + 1) * 4);
  int* cur       = (int*)alloc((size_t)2*N * 4);
  int* rows      = (int*)alloc((size_t)2*E * 4);
  int* srcs      = (int*)alloc((size_t)2*E * 4);
  int* part      = (int*)alloc(4096 * 4);
  float* Ein     = (float*)alloc((size_t)N*16*4);
  float* Eout    = (float*)alloc((size_t)N*16*4);
  float* Sin     = (float*)alloc((size_t)N*64*4);
  float* Sout    = (float*)alloc((size_t)N*64*4);
  float* hA      = (float*)alloc((size_t)N*64*4);
  float* hB      = (float*)alloc((size_t)N*64*4);
  u16* bA        = (u16*)alloc((size_t)R*80*64*8*2);   // 80 frags/round, 1 KB each
  u16* bB        = (u16*)alloc((size_t)R*96*64*8*2);   // 96 frags/round
  float* partial = (float*)alloc((size_t)NB5*128*4);

  hipMemsetAsync(off, 0, ((size_t)2*N+1)*4, stream);

  int eb = (E + 255)/256;
  k_count<<<eb, 256, 0, stream>>>(uidx, vidx, off, N, E);
  int M = 2*N;
  int nb = (M + 255)/256;
  k_scan1<<<nb, 256, 0, stream>>>(off, part, M);
  k_scan2<<<1, 1024, 0, stream>>>(part, nb);
  k_scan3<<<nb, 256, 0, stream>>>(off, part, cur, M, 2*E);
  k_fill<<<eb, 256, 0, stream>>>(uidx, vidx, cur, rows, srcs, N, E);
  int wb = (N + 3)/4;
  k_einout<<<wb, 256, 0, stream>>>(ev, off, rows, Ein, Eout, N);

  // one-time fp16 B-fragment builds (weights are round-indexed, launch-constant)
  k_preA<<<R*80, 64, 0, stream>>>(Wef, bef, Wer, ber, bA);
  k_preB<<<R*96, 64, 0, stream>>>(Wih, Whh, bih, bhh, bB);

  int nT = (N + 63)/64;
  int ab = (2*N + 3)/4;
  const float* hcur = nodev;
  float* bufs[2] = {hA, hB};
  for(int r = 0; r < R; ++r){
    k_aggr<<<ab, 256, 0, stream>>>(hcur, off, srcs, Sin, Sout, N);
    float* hn = bufs[r & 1];
    k34_mfma<<<nT, 512, 0, stream>>>(hcur, Sin, Sout, Ein, Eout, off,
                                     bA + (size_t)r*80*64*8,
                                     bB + (size_t)r*96*64*8,
                                     hn, N);
    hcur = hn;
  }
  k5_read<<<NB5, 512, 0, stream>>>(hcur, Wfm, bfm, Wgm, bgm, partial, N, nT);
  k6_dec<<<1, 256, 0, stream>>>(partial, NB5, hcur, Wdec, bdec, tgt, (float*)d_out);
}